// Round 2
// baseline (511.978 us; speedup 1.0000x reference)
//
#include <hip/hip_runtime.h>
#include <math.h>

#define Bc 4
#define Lc 200
#define Hc 256
#define NHc 4
#define HSc 64
#define NBc 2
#define Mtot (Bc*Lc)   // 800
#define TDW 264        // padded width for 257-entry table scores

static __device__ __forceinline__ float neg_fill() { return -4294967295.0f; } // -(2^32)+1

// ---------------- embedding + keep mask ----------------
__global__ void embed_k(const int* __restrict__ logs, const float* __restrict__ emb,
                        float* __restrict__ seqs) {
  int idx = blockIdx.x * 256 + threadIdx.x;
  int hcol = idx & (Hc - 1);
  int bl = idx >> 8;
  int tok = logs[bl];
  seqs[idx] = (tok == 0) ? 0.f : emb[tok * Hc + hcol];
}

// ---------------- layernorm over H=256, one block per row ----------------
__global__ void ln_k(const float* __restrict__ x, const float* __restrict__ g,
                     const float* __restrict__ bt, float* __restrict__ y) {
  int row = blockIdx.x;
  int t = threadIdx.x;
  float v = x[row * Hc + t];
  float a = v, sq = v * v;
  for (int o = 32; o; o >>= 1) { a += __shfl_down(a, o); sq += __shfl_down(sq, o); }
  __shared__ float s1[4], s2[4];
  __shared__ float mS, rS;
  int wave = t >> 6, lane = t & 63;
  if (lane == 0) { s1[wave] = a; s2[wave] = sq; }
  __syncthreads();
  if (t == 0) {
    float sum = s1[0] + s1[1] + s1[2] + s1[3];
    float ssq = s2[0] + s2[1] + s2[2] + s2[3];
    float m = sum * (1.f / Hc);
    float var = ssq * (1.f / Hc) - m * m;
    mS = m;
    rS = 1.f / sqrtf(var + 1e-8f);
  }
  __syncthreads();
  y[row * Hc + t] = (v - mS) * rS * g[t] + bt[t];
}

// ---------------- GEMM: out[M,N] = A[M,K] @ W[N,K]^T + bias ----
// FUSE: 0=+bias ; 1=relu ; 2=(+bias+X)*keep ; 3=+pK[m%L] ; 4=+pV[m%L]
template <int FUSE>
__global__ void gemm_k(const float* __restrict__ A, const float* __restrict__ W,
                       const float* __restrict__ bias, const float* __restrict__ X,
                       const int* __restrict__ logs, float* __restrict__ out) {
  __shared__ float As[32][33];
  __shared__ float Ws[32][33];
  int m0 = blockIdx.x * 32, n0 = blockIdx.y * 32;
  int t = threadIdx.x;
  int tx = t & 15, ty = t >> 4;
  int lr = t >> 3, lc = (t & 7) * 4;
  float c00 = 0.f, c01 = 0.f, c10 = 0.f, c11 = 0.f;
  for (int k0 = 0; k0 < Hc; k0 += 32) {
    float4 av = *(const float4*)&A[(m0 + lr) * Hc + k0 + lc];
    float4 wv = *(const float4*)&W[(n0 + lr) * Hc + k0 + lc];
    As[lr][lc] = av.x; As[lr][lc + 1] = av.y; As[lr][lc + 2] = av.z; As[lr][lc + 3] = av.w;
    Ws[lr][lc] = wv.x; Ws[lr][lc + 1] = wv.y; Ws[lr][lc + 2] = wv.z; Ws[lr][lc + 3] = wv.w;
    __syncthreads();
#pragma unroll
    for (int k = 0; k < 32; ++k) {
      float a0 = As[2 * ty][k], a1 = As[2 * ty + 1][k];
      float w0 = Ws[2 * tx][k], w1 = Ws[2 * tx + 1][k];
      c00 += a0 * w0; c01 += a0 * w1; c10 += a1 * w0; c11 += a1 * w1;
    }
    __syncthreads();
  }
  int m = m0 + 2 * ty, n = n0 + 2 * tx;
  float b0 = bias[n], b1v = bias[n + 1];
  float r00 = c00 + b0, r01 = c01 + b1v, r10 = c10 + b0, r11 = c11 + b1v;
  if (FUSE == 1) {
    r00 = fmaxf(r00, 0.f); r01 = fmaxf(r01, 0.f);
    r10 = fmaxf(r10, 0.f); r11 = fmaxf(r11, 0.f);
  } else if (FUSE == 2) {
    float k0m = (logs[m] != 0) ? 1.f : 0.f;
    float k1m = (logs[m + 1] != 0) ? 1.f : 0.f;
    r00 = (r00 + X[m * Hc + n]) * k0m;
    r01 = (r01 + X[m * Hc + n + 1]) * k0m;
    r10 = (r10 + X[(m + 1) * Hc + n]) * k1m;
    r11 = (r11 + X[(m + 1) * Hc + n + 1]) * k1m;
  } else if (FUSE == 3 || FUSE == 4) {
    int p0 = m % Lc, p1 = (m + 1) % Lc;
    r00 += X[p0 * Hc + n];     r01 += X[p0 * Hc + n + 1];
    r10 += X[p1 * Hc + n];     r11 += X[p1 * Hc + n + 1];
  }
  out[m * Hc + n] = r00; out[m * Hc + n + 1] = r01;
  out[(m + 1) * Hc + n] = r10; out[(m + 1) * Hc + n + 1] = r11;
}

// ---------------- T/D table scores: T[h][bq][c] = Q_h[bq] . tab_h[c] ----------
// grid (25, 9, 8): z = table*4 + h
__global__ void gemmTD_k(const float* __restrict__ Q,
                         const float* __restrict__ tKt, const float* __restrict__ dKt,
                         float* __restrict__ Tb, float* __restrict__ Db) {
  int z = blockIdx.z;
  int table = z >> 2, h = z & 3;
  const float* tab = table ? dKt : tKt;
  float* outb = table ? Db : Tb;
  int m0 = blockIdx.x * 32, n0 = blockIdx.y * 32;
  __shared__ float As[32][65];
  __shared__ float Bs[32][65];
  int t = threadIdx.x;
  int lr = t >> 3, lc = (t & 7) * 8;
  {
    const float* ar = &Q[(m0 + lr) * Hc + h * HSc];
#pragma unroll
    for (int j = 0; j < 8; ++j) As[lr][lc + j] = ar[lc + j];
    int c = n0 + lr;
    if (c < 257) {
      const float* br = &tab[c * Hc + h * HSc];
#pragma unroll
      for (int j = 0; j < 8; ++j) Bs[lr][lc + j] = br[lc + j];
    } else {
#pragma unroll
      for (int j = 0; j < 8; ++j) Bs[lr][lc + j] = 0.f;
    }
  }
  __syncthreads();
  int tx = t & 15, ty = t >> 4;
  float c00 = 0.f, c01 = 0.f, c10 = 0.f, c11 = 0.f;
#pragma unroll
  for (int k = 0; k < HSc; ++k) {
    float a0 = As[2 * ty][k], a1 = As[2 * ty + 1][k];
    float b0 = Bs[2 * tx][k], b1 = Bs[2 * tx + 1][k];
    c00 += a0 * b0; c01 += a0 * b1; c10 += a1 * b0; c11 += a1 * b1;
  }
  int m = m0 + 2 * ty, n = n0 + 2 * tx;
  float* o0 = &outb[(size_t)(h * Mtot + m) * TDW];
  float* o1 = &outb[(size_t)(h * Mtot + m + 1) * TDW];
  if (n < 257)     { o0[n] = c00;     o1[n] = c10; }
  if (n + 1 < 257) { o0[n + 1] = c01; o1[n + 1] = c11; }
}

// ---------------- S0[z][q][k] = Q_h[b,q] . K'_h[b,k],  z = h*4+b ----------
// grid (7, 7, 16)
__global__ void gemmS0_k(const float* __restrict__ Q, const float* __restrict__ Kp,
                         float* __restrict__ S0) {
  int z = blockIdx.z;
  int h = z >> 2, b = z & 3;
  int m0 = blockIdx.x * 32, n0 = blockIdx.y * 32;
  __shared__ float As[32][65];
  __shared__ float Bs[32][65];
  int t = threadIdx.x;
  int lr = t >> 3, lc = (t & 7) * 8;
  {
    int mr = m0 + lr;
    if (mr < Lc) {
      const float* ar = &Q[(b * Lc + mr) * Hc + h * HSc];
#pragma unroll
      for (int j = 0; j < 8; ++j) As[lr][lc + j] = ar[lc + j];
    } else {
#pragma unroll
      for (int j = 0; j < 8; ++j) As[lr][lc + j] = 0.f;
    }
    int nr = n0 + lr;
    if (nr < Lc) {
      const float* br = &Kp[(b * Lc + nr) * Hc + h * HSc];
#pragma unroll
      for (int j = 0; j < 8; ++j) Bs[lr][lc + j] = br[lc + j];
    } else {
#pragma unroll
      for (int j = 0; j < 8; ++j) Bs[lr][lc + j] = 0.f;
    }
  }
  __syncthreads();
  int tx = t & 15, ty = t >> 4;
  float c00 = 0.f, c01 = 0.f, c10 = 0.f, c11 = 0.f;
#pragma unroll
  for (int k = 0; k < HSc; ++k) {
    float a0 = As[2 * ty][k], a1 = As[2 * ty + 1][k];
    float b0 = Bs[2 * tx][k], b1 = Bs[2 * tx + 1][k];
    c00 += a0 * b0; c01 += a0 * b1; c10 += a1 * b0; c11 += a1 * b1;
  }
  int m = m0 + 2 * ty, n = n0 + 2 * tx;
  size_t base = (size_t)z * Lc * Lc;
  if (m < Lc) {
    if (n < Lc)     S0[base + (size_t)m * Lc + n] = c00;
    if (n + 1 < Lc) S0[base + (size_t)m * Lc + n + 1] = c01;
  }
  if (m + 1 < Lc) {
    if (n < Lc)     S0[base + (size_t)(m + 1) * Lc + n] = c10;
    if (n + 1 < Lc) S0[base + (size_t)(m + 1) * Lc + n + 1] = c11;
  }
}

// ---------------- score assembly + softmax + histogram ----------------
// block per (b,q), wave h per head. S0 -> A in place; Tb/Db -> Wt/Wd in place.
__global__ void softhist_k(float* __restrict__ S0, float* __restrict__ Tb,
                           float* __restrict__ Db,
                           const int* __restrict__ tm, const int* __restrict__ dm,
                           const int* __restrict__ logs) {
  int bq = blockIdx.x;
  int b = bq / Lc, q = bq - b * Lc;
  int t = threadIdx.x, h = t >> 6, lane = t & 63;
  __shared__ float sS[NHc][Lc];
  __shared__ int sTM[Lc], sDM[Lc];
  __shared__ float bins[2][NHc][TDW];
  for (int i = t; i < 2 * NHc * TDW; i += 256) (&bins[0][0][0])[i] = 0.f;
  if (t < Lc) { sTM[t] = tm[bq * Lc + t]; sDM[t] = dm[bq * Lc + t]; }
  __syncthreads();
  size_t trow = (size_t)(h * Mtot + bq) * TDW;
  int z = h * 4 + b;
  size_t srow = ((size_t)z * Lc + q) * Lc;
  for (int k = lane; k < Lc; k += 64) {
    float s = S0[srow + k] + Tb[trow + sTM[k]] + Db[trow + sDM[k]];
    bool masked = (k > q) || (logs[b * Lc + k] == 0);
    sS[h][k] = masked ? neg_fill() : s * 0.125f;
  }
  float mx = -INFINITY;
  for (int k = lane; k < Lc; k += 64) mx = fmaxf(mx, sS[h][k]);
  for (int o = 32; o; o >>= 1) mx = fmaxf(mx, __shfl_xor(mx, o));
  float sum = 0.f;
  for (int k = lane; k < Lc; k += 64) {
    float e = expf(sS[h][k] - mx);
    sS[h][k] = e;
    sum += e;
  }
  for (int o = 32; o; o >>= 1) sum += __shfl_xor(sum, o);
  float r = 1.f / sum;
  __syncthreads();   // all T/D reads done before overwrite below
  for (int k = lane; k < Lc; k += 64) {
    float a = sS[h][k] * r;
    S0[srow + k] = a;                       // A in place
    atomicAdd(&bins[0][h][sTM[k]], a);
    atomicAdd(&bins[1][h][sDM[k]], a);
  }
  __syncthreads();
  for (int c = lane; c < TDW; c += 64) {
    Tb[trow + c] = bins[0][h][c];           // Wt in place
    Db[trow + c] = bins[1][h][c];           // Wd in place
  }
}

// ---------------- O0[bq][h*64+d] = sum_k A[z][q][k] * V'[b,k,h,d] ----------
// grid (7, 1, 16)
__global__ void gemmO0_k(const float* __restrict__ A, const float* __restrict__ Vp,
                         float* __restrict__ O) {
  int z = blockIdx.z;
  int h = z >> 2, b = z & 3;
  int m0 = blockIdx.x * 32;
  __shared__ float As[32][33];
  __shared__ float Bs[32][65];
  int t = threadIdx.x;
  int ty = t >> 6, tx = t & 63;
  int lr = t >> 3, lc4 = (t & 7) * 4, lc8 = (t & 7) * 8;
  float acc[8];
#pragma unroll
  for (int r = 0; r < 8; ++r) acc[r] = 0.f;
  size_t abase = (size_t)z * Lc * Lc;
  for (int k0 = 0; k0 < Lc; k0 += 32) {
    __syncthreads();
    {
      int mr = m0 + lr;
#pragma unroll
      for (int j = 0; j < 4; ++j) {
        int kk = k0 + lc4 + j;
        As[lr][lc4 + j] = (mr < Lc && kk < Lc) ? A[abase + (size_t)mr * Lc + kk] : 0.f;
      }
      int kr = k0 + lr;
      if (kr < Lc) {
        const float* br = &Vp[(b * Lc + kr) * Hc + h * HSc];
#pragma unroll
        for (int j = 0; j < 8; ++j) Bs[lr][lc8 + j] = br[lc8 + j];
      } else {
#pragma unroll
        for (int j = 0; j < 8; ++j) Bs[lr][lc8 + j] = 0.f;
      }
    }
    __syncthreads();
#pragma unroll
    for (int k = 0; k < 32; ++k) {
      float bv = Bs[k][tx];
#pragma unroll
      for (int r = 0; r < 8; ++r) acc[r] += As[ty * 8 + r][k] * bv;
    }
  }
#pragma unroll
  for (int r = 0; r < 8; ++r) {
    int m = m0 + ty * 8 + r;
    if (m < Lc) O[(b * Lc + m) * Hc + h * HSc + tx] = acc[r];
  }
}

// ---------------- o_tab + residual: seqs = Qn + O0 + Wt.tV_h + Wd.dV_h ------
// grid (200, 4): 4 bq rows per block, head h; thread = (row 0..3, d 0..63)
__global__ void otab_k(const float* __restrict__ Wt, const float* __restrict__ Wd,
                       const float* __restrict__ tV, const float* __restrict__ dV,
                       const float* __restrict__ O0, const float* __restrict__ Qn,
                       float* __restrict__ seqs) {
  int r0 = blockIdx.x * 4;
  int h = blockIdx.y;
  int t = threadIdx.x;
  int row = t >> 6, d = t & 63;
  __shared__ float tVs[64][64];
  __shared__ float dVs[64][64];
  __shared__ float Wts[4][65];
  __shared__ float Wds[4][65];
  float acc = 0.f;
  for (int c0 = 0; c0 < 257; c0 += 64) {
    __syncthreads();
    {
      int lr = t >> 2, lc = (t & 3) * 16;
      int c = c0 + lr;
      if (c < 257) {
        const float* tr = &tV[c * Hc + h * HSc];
        const float* dr = &dV[c * Hc + h * HSc];
#pragma unroll
        for (int j = 0; j < 16; ++j) { tVs[lr][lc + j] = tr[lc + j]; dVs[lr][lc + j] = dr[lc + j]; }
      } else {
#pragma unroll
        for (int j = 0; j < 16; ++j) { tVs[lr][lc + j] = 0.f; dVs[lr][lc + j] = 0.f; }
      }
      int wr = t >> 6, wc = t & 63;
      int cc = c0 + wc;
      size_t wrow = (size_t)(h * Mtot + r0 + wr) * TDW;
      Wts[wr][wc] = (cc < 257) ? Wt[wrow + cc] : 0.f;
      Wds[wr][wc] = (cc < 257) ? Wd[wrow + cc] : 0.f;
    }
    __syncthreads();
#pragma unroll 8
    for (int k = 0; k < 64; ++k)
      acc += Wts[row][k] * tVs[k][d] + Wds[row][k] * dVs[k][d];
  }
  int idx = (r0 + row) * Hc + h * HSc + d;
  seqs[idx] = Qn[idx] + O0[idx] + acc;
}

extern "C" void kernel_launch(void* const* d_in, const int* in_sizes, int n_in,
                              void* d_out, int out_size, void* d_ws, size_t ws_size,
                              hipStream_t stream) {
  const int* logs = (const int*)d_in[0];
  const int* tm   = (const int*)d_in[1];
  const int* dm   = (const int*)d_in[2];
  const float* item = (const float*)d_in[3];
  const float* pK = (const float*)d_in[4];
  const float* pV = (const float*)d_in[5];
  const float* tK = (const float*)d_in[6];
  const float* tV = (const float*)d_in[7];
  const float* dK = (const float*)d_in[8];
  const float* dV = (const float*)d_in[9];
  const float* ln1_g = (const float*)d_in[10];
  const float* ln1_b = (const float*)d_in[11];
  const float* Wq = (const float*)d_in[12];
  const float* bq = (const float*)d_in[13];
  const float* Wk = (const float*)d_in[14];
  const float* bk = (const float*)d_in[15];
  const float* Wv = (const float*)d_in[16];
  const float* bv = (const float*)d_in[17];
  const float* ln2_g = (const float*)d_in[18];
  const float* ln2_b = (const float*)d_in[19];
  const float* W1 = (const float*)d_in[20];
  const float* b1 = (const float*)d_in[21];
  const float* W2 = (const float*)d_in[22];
  const float* b2 = (const float*)d_in[23];
  const float* lnf_g = (const float*)d_in[24];
  const float* lnf_b = (const float*)d_in[25];

  const int NROW = Mtot * Hc;          // 204800
  float* ws = (float*)d_ws;
  float* sSeqs = ws + 0 * NROW;
  float* sQn   = ws + 1 * NROW;
  float* sQ    = ws + 2 * NROW;
  float* sK    = ws + 3 * NROW;
  float* sV    = ws + 4 * NROW;
  float* sX    = ws + 5 * NROW;
  float* sH    = ws + 6 * NROW;
  float* sO    = ws + 7 * NROW;
  float* S0    = sO + NROW;            // 16*200*200 = 640000 floats
  float* Tb    = S0 + 16 * Lc * Lc;    // 4*800*264 = 844800 floats
  float* Db    = Tb + NHc * Mtot * TDW;

  embed_k<<<NROW / 256, 256, 0, stream>>>(logs, item, sSeqs);

  dim3 gg(Mtot / 32, Hc / 32);
  dim3 gTD(Mtot / 32, 9, 8);
  dim3 gS0(7, 7, 16);
  dim3 gO0(7, 1, 16);
  dim3 gOt(Mtot / 4, NHc);
  for (int i = 0; i < NBc; ++i) {
    ln_k<<<Mtot, Hc, 0, stream>>>(sSeqs, ln1_g + i * Hc, ln1_b + i * Hc, sQn);
    gemm_k<0><<<gg, 256, 0, stream>>>(sQn,   Wq + i * Hc * Hc, bq + i * Hc, nullptr, nullptr, sQ);
    gemm_k<3><<<gg, 256, 0, stream>>>(sSeqs, Wk + i * Hc * Hc, bk + i * Hc, pK, nullptr, sK);
    gemm_k<4><<<gg, 256, 0, stream>>>(sSeqs, Wv + i * Hc * Hc, bv + i * Hc, pV, nullptr, sV);
    gemmTD_k<<<gTD, 256, 0, stream>>>(sQ, tK, dK, Tb, Db);
    gemmS0_k<<<gS0, 256, 0, stream>>>(sQ, sK, S0);
    softhist_k<<<Mtot, 256, 0, stream>>>(S0, Tb, Db, tm, dm, logs);
    gemmO0_k<<<gO0, 256, 0, stream>>>(S0, sV, sO);
    otab_k<<<gOt, 256, 0, stream>>>(Tb, Db, tV, dV, sO, sQn, sSeqs);
    ln_k<<<Mtot, Hc, 0, stream>>>(sSeqs, ln2_g + i * Hc, ln2_b + i * Hc, sX);
    gemm_k<1><<<gg, 256, 0, stream>>>(sX, W1 + i * Hc * Hc, b1 + i * Hc, nullptr, nullptr, sH);
    gemm_k<2><<<gg, 256, 0, stream>>>(sH, W2 + i * Hc * Hc, b2 + i * Hc, sX, logs, sSeqs);
  }
  ln_k<<<Mtot, Hc, 0, stream>>>(sSeqs, lnf_g, lnf_b, (float*)d_out);
}

// Round 3
// 320.866 us; speedup vs baseline: 1.5956x; 1.5956x over previous
//
#include <hip/hip_runtime.h>
#include <math.h>

#define Bc 4
#define Lc 200
#define Hc 256
#define NHc 4
#define HSc 64
#define NBc 2
#define Mtot (Bc*Lc)   // 800
#define QSPLIT 8       // q-interleave factor for attention kernels
#define TPAD 65        // LDS row stride (floats) for 257-row tables

static __device__ __forceinline__ float neg_fill() { return -4294967295.0f; } // -(2^32)+1

// ---------------- embedding + keep mask ----------------
__global__ void embed_k(const int* __restrict__ logs, const float* __restrict__ emb,
                        float* __restrict__ seqs) {
  int idx = blockIdx.x * 256 + threadIdx.x;
  int hcol = idx & (Hc - 1);
  int bl = idx >> 8;
  int tok = logs[bl];
  seqs[idx] = (tok == 0) ? 0.f : emb[tok * Hc + hcol];
}

// ---------------- layernorm over H=256, one block per row ----------------
__global__ void ln_k(const float* __restrict__ x, const float* __restrict__ g,
                     const float* __restrict__ bt, float* __restrict__ y) {
  int row = blockIdx.x;
  int t = threadIdx.x;
  float v = x[row * Hc + t];
  float a = v, sq = v * v;
  for (int o = 32; o; o >>= 1) { a += __shfl_down(a, o); sq += __shfl_down(sq, o); }
  __shared__ float s1[4], s2[4];
  __shared__ float mS, rS;
  int wave = t >> 6, lane = t & 63;
  if (lane == 0) { s1[wave] = a; s2[wave] = sq; }
  __syncthreads();
  if (t == 0) {
    float sum = s1[0] + s1[1] + s1[2] + s1[3];
    float ssq = s2[0] + s2[1] + s2[2] + s2[3];
    float m = sum * (1.f / Hc);
    float var = ssq * (1.f / Hc) - m * m;
    mS = m;
    rS = 1.f / sqrtf(var + 1e-8f);
  }
  __syncthreads();
  y[row * Hc + t] = (v - mS) * rS * g[t] + bt[t];
}

// ---------------- GEMM: out[M,N] = A[M,K] @ W[N,K]^T + bias ----
// FUSE: 0=+bias ; 1=relu ; 2=(+bias+X)*keep ; 3=+pK[m%L] ; 4=+pV[m%L]
template <int FUSE>
__global__ void gemm_k(const float* __restrict__ A, const float* __restrict__ W,
                       const float* __restrict__ bias, const float* __restrict__ X,
                       const int* __restrict__ logs, float* __restrict__ out) {
  __shared__ float As[32][33];
  __shared__ float Ws[32][33];
  int m0 = blockIdx.x * 32, n0 = blockIdx.y * 32;
  int t = threadIdx.x;
  int tx = t & 15, ty = t >> 4;
  int lr = t >> 3, lc = (t & 7) * 4;
  float c00 = 0.f, c01 = 0.f, c10 = 0.f, c11 = 0.f;
  for (int k0 = 0; k0 < Hc; k0 += 32) {
    float4 av = *(const float4*)&A[(m0 + lr) * Hc + k0 + lc];
    float4 wv = *(const float4*)&W[(n0 + lr) * Hc + k0 + lc];
    As[lr][lc] = av.x; As[lr][lc + 1] = av.y; As[lr][lc + 2] = av.z; As[lr][lc + 3] = av.w;
    Ws[lr][lc] = wv.x; Ws[lr][lc + 1] = wv.y; Ws[lr][lc + 2] = wv.z; Ws[lr][lc + 3] = wv.w;
    __syncthreads();
#pragma unroll
    for (int k = 0; k < 32; ++k) {
      float a0 = As[2 * ty][k], a1 = As[2 * ty + 1][k];
      float w0 = Ws[2 * tx][k], w1 = Ws[2 * tx + 1][k];
      c00 += a0 * w0; c01 += a0 * w1; c10 += a1 * w0; c11 += a1 * w1;
    }
    __syncthreads();
  }
  int m = m0 + 2 * ty, n = n0 + 2 * tx;
  float b0 = bias[n], b1v = bias[n + 1];
  float r00 = c00 + b0, r01 = c01 + b1v, r10 = c10 + b0, r11 = c11 + b1v;
  if (FUSE == 1) {
    r00 = fmaxf(r00, 0.f); r01 = fmaxf(r01, 0.f);
    r10 = fmaxf(r10, 0.f); r11 = fmaxf(r11, 0.f);
  } else if (FUSE == 2) {
    float k0m = (logs[m] != 0) ? 1.f : 0.f;
    float k1m = (logs[m + 1] != 0) ? 1.f : 0.f;
    r00 = (r00 + X[m * Hc + n]) * k0m;
    r01 = (r01 + X[m * Hc + n + 1]) * k0m;
    r10 = (r10 + X[(m + 1) * Hc + n]) * k1m;
    r11 = (r11 + X[(m + 1) * Hc + n + 1]) * k1m;
  } else if (FUSE == 3 || FUSE == 4) {
    int p0 = m % Lc, p1 = (m + 1) % Lc;
    r00 += X[p0 * Hc + n];     r01 += X[p0 * Hc + n + 1];
    r10 += X[p1 * Hc + n];     r11 += X[p1 * Hc + n + 1];
  }
  out[m * Hc + n] = r00; out[m * Hc + n + 1] = r01;
  out[(m + 1) * Hc + n] = r10; out[(m + 1) * Hc + n + 1] = r11;
}

// ---------------- attention scores + softmax -> A ----------------
// grid (NHc, Bc, QSPLIT); block 256 (4 waves). LDS-staged tK/dK head slices.
__global__ __launch_bounds__(256, 1)
void score_k(const float* __restrict__ Q, const float* __restrict__ Kp,
             const float* __restrict__ tK, const float* __restrict__ dK,
             const int* __restrict__ tm, const int* __restrict__ dm,
             const int* __restrict__ logs, float* __restrict__ A) {
  int h = blockIdx.x, b = blockIdx.y, qs = blockIdx.z;
  __shared__ float tKs[257 * TPAD];
  __shared__ float dKs[257 * TPAD];
  int t = threadIdx.x;
  for (int i = t; i < 257 * HSc; i += 256) {
    int r = i >> 6, c = i & 63;
    tKs[r * TPAD + c] = tK[r * Hc + h * HSc + c];
    dKs[r * TPAD + c] = dK[r * Hc + h * HSc + c];
  }
  __syncthreads();
  int w = t >> 6, lane = t & 63;
  int z = h * 4 + b;
  for (int j = w; j < 25; j += 4) {
    int q = qs + QSPLIT * j;
    int m = b * Lc + q;
    int arow = __builtin_amdgcn_readfirstlane((z * Lc + q) * Lc);
    if (logs[b * Lc + q] == 0) {           // pad query row: A := 0 (keep-mask zeroes it later anyway)
      for (int k = lane; k < Lc; k += 64) A[arow + k] = 0.f;
      continue;
    }
    const float* Qrow = Q + __builtin_amdgcn_readfirstlane(m * Hc + h * HSc); // wave-uniform -> SMEM
    const int* tmr = tm + __builtin_amdgcn_readfirstlane(m * Lc);
    const int* dmr = dm + __builtin_amdgcn_readfirstlane(m * Lc);
    int np = (q >> 6) + 1;                 // ceil((q+1)/64)
    float sv[4];
    float mx = neg_fill();
#pragma unroll 4
    for (int p = 0; p < 4; ++p) {
      if (p >= np) { sv[p] = neg_fill(); continue; }
      int k = p * 64 + lane;
      float s = neg_fill();
      if (k <= q) {
        int ti = tmr[k], di = dmr[k];
        const float* Kr = &Kp[(b * Lc + k) * Hc + h * HSc];
        const float* tr = &tKs[ti * TPAD];
        const float* dr = &dKs[di * TPAD];
        float acc = 0.f;
#pragma unroll
        for (int d = 0; d < HSc; d += 4) {
          float4 kv = *(const float4*)(Kr + d);
          acc += Qrow[d + 0] * (kv.x + tr[d + 0] + dr[d + 0]);
          acc += Qrow[d + 1] * (kv.y + tr[d + 1] + dr[d + 1]);
          acc += Qrow[d + 2] * (kv.z + tr[d + 2] + dr[d + 2]);
          acc += Qrow[d + 3] * (kv.w + tr[d + 3] + dr[d + 3]);
        }
        s = acc * 0.125f;
      }
      sv[p] = s;
      mx = fmaxf(mx, s);
    }
#pragma unroll
    for (int o = 32; o; o >>= 1) mx = fmaxf(mx, __shfl_xor(mx, o));
    float sum = 0.f;
    float ev[4];
#pragma unroll
    for (int p = 0; p < 4; ++p) {
      float e = (p < np) ? __expf(sv[p] - mx) : 0.f;
      ev[p] = e;
      sum += e;
    }
#pragma unroll
    for (int o = 32; o; o >>= 1) sum += __shfl_xor(sum, o);
    float r = 1.f / sum;
#pragma unroll 4
    for (int p = 0; p < 4; ++p) {
      if (p >= np) continue;
      int k = p * 64 + lane;
      if (k < Lc) A[arow + k] = ev[p] * r;
    }
  }
}

// ---------------- attention output + residual ----------------
// grid (NHc, Bc, QSPLIT); block 256. LDS-staged tV/dV head slices.
// seqs[m,h*64+d] = Qn[...] + sum_k A[q,k]*(V'[k,d] + tV[tm,d] + dV[dm,d])
__global__ __launch_bounds__(256, 1)
void out_k(const float* __restrict__ A, const float* __restrict__ Vp,
           const float* __restrict__ tV, const float* __restrict__ dV,
           const int* __restrict__ tm, const int* __restrict__ dm,
           const float* __restrict__ Qn, float* __restrict__ seqs) {
  int h = blockIdx.x, b = blockIdx.y, qs = blockIdx.z;
  __shared__ float tVs[257 * TPAD];
  __shared__ float dVs[257 * TPAD];
  int t = threadIdx.x;
  for (int i = t; i < 257 * HSc; i += 256) {
    int r = i >> 6, c = i & 63;
    tVs[r * TPAD + c] = tV[r * Hc + h * HSc + c];
    dVs[r * TPAD + c] = dV[r * Hc + h * HSc + c];
  }
  __syncthreads();
  int w = t >> 6, lane = t & 63;
  int z = h * 4 + b;
  for (int j = w; j < 25; j += 4) {
    int q = qs + QSPLIT * j;
    int m = b * Lc + q;
    const float* Ar = A + __builtin_amdgcn_readfirstlane((z * Lc + q) * Lc);
    const int* tmr = tm + __builtin_amdgcn_readfirstlane(m * Lc);
    const int* dmr = dm + __builtin_amdgcn_readfirstlane(m * Lc);
    float acc = 0.f;
#pragma unroll 4
    for (int k = 0; k <= q; ++k) {
      float av = Ar[k];
      int ti = tmr[k], di = dmr[k];
      float vv = Vp[(b * Lc + k) * Hc + h * HSc + lane]
               + tVs[ti * TPAD + lane] + dVs[di * TPAD + lane];
      acc = fmaf(av, vv, acc);
    }
    int oi = m * Hc + h * HSc + lane;
    seqs[oi] = Qn[oi] + acc;
  }
}

extern "C" void kernel_launch(void* const* d_in, const int* in_sizes, int n_in,
                              void* d_out, int out_size, void* d_ws, size_t ws_size,
                              hipStream_t stream) {
  const int* logs = (const int*)d_in[0];
  const int* tm   = (const int*)d_in[1];
  const int* dm   = (const int*)d_in[2];
  const float* item = (const float*)d_in[3];
  const float* pK = (const float*)d_in[4];
  const float* pV = (const float*)d_in[5];
  const float* tK = (const float*)d_in[6];
  const float* tV = (const float*)d_in[7];
  const float* dK = (const float*)d_in[8];
  const float* dV = (const float*)d_in[9];
  const float* ln1_g = (const float*)d_in[10];
  const float* ln1_b = (const float*)d_in[11];
  const float* Wq = (const float*)d_in[12];
  const float* bq = (const float*)d_in[13];
  const float* Wk = (const float*)d_in[14];
  const float* bk = (const float*)d_in[15];
  const float* Wv = (const float*)d_in[16];
  const float* bv = (const float*)d_in[17];
  const float* ln2_g = (const float*)d_in[18];
  const float* ln2_b = (const float*)d_in[19];
  const float* W1 = (const float*)d_in[20];
  const float* b1 = (const float*)d_in[21];
  const float* W2 = (const float*)d_in[22];
  const float* b2 = (const float*)d_in[23];
  const float* lnf_g = (const float*)d_in[24];
  const float* lnf_b = (const float*)d_in[25];

  const int NROW = Mtot * Hc;          // 204800
  float* ws = (float*)d_ws;
  float* sSeqs = ws + 0 * NROW;
  float* sQn   = ws + 1 * NROW;
  float* sQ    = ws + 2 * NROW;
  float* sK    = ws + 3 * NROW;
  float* sV    = ws + 4 * NROW;
  float* sX    = ws + 5 * NROW;
  float* sH    = ws + 6 * NROW;
  float* Abuf  = ws + 7 * NROW;        // 16*200*200 = 640000 floats

  embed_k<<<NROW / 256, 256, 0, stream>>>(logs, item, sSeqs);

  dim3 gg(Mtot / 32, Hc / 32);
  dim3 ga(NHc, Bc, QSPLIT);            // 128 blocks
  for (int i = 0; i < NBc; ++i) {
    ln_k<<<Mtot, Hc, 0, stream>>>(sSeqs, ln1_g + i * Hc, ln1_b + i * Hc, sQn);
    gemm_k<0><<<gg, 256, 0, stream>>>(sQn,   Wq + i * Hc * Hc, bq + i * Hc, nullptr, nullptr, sQ);
    gemm_k<3><<<gg, 256, 0, stream>>>(sSeqs, Wk + i * Hc * Hc, bk + i * Hc, pK, nullptr, sK);
    gemm_k<4><<<gg, 256, 0, stream>>>(sSeqs, Wv + i * Hc * Hc, bv + i * Hc, pV, nullptr, sV);
    score_k<<<ga, 256, 0, stream>>>(sQ, sK, tK, dK, tm, dm, logs, Abuf);
    out_k<<<ga, 256, 0, stream>>>(Abuf, sV, tV, dV, tm, dm, sQn, sSeqs);
    ln_k<<<Mtot, Hc, 0, stream>>>(sSeqs, ln2_g + i * Hc, ln2_b + i * Hc, sX);
    gemm_k<1><<<gg, 256, 0, stream>>>(sX, W1 + i * Hc * Hc, b1 + i * Hc, nullptr, nullptr, sH);
    gemm_k<2><<<gg, 256, 0, stream>>>(sH, W2 + i * Hc * Hc, b2 + i * Hc, sX, logs, sSeqs);
  }
  ln_k<<<Mtot, Hc, 0, stream>>>(sSeqs, lnf_g, lnf_b, (float*)d_out);
}

// Round 5
// 229.826 us; speedup vs baseline: 2.2277x; 1.3961x over previous
//
#include <hip/hip_runtime.h>
#include <math.h>

typedef __fp16 h2 __attribute__((ext_vector_type(2)));

#define Bc 4
#define Lc 200
#define Hc 256
#define NHc 4
#define HSc 64
#define NBc 2
#define Mtot (Bc*Lc)   // 800
#define QS2 32         // attention q-split (grid.z) -> 512 blocks
#define TROW 34        // LDS table row stride in u32 (68 halfs = 136B, odd uint2 stride)

static __device__ __forceinline__ float neg_fill() { return -4294967295.0f; }

static __device__ __forceinline__ uint pkh2(float a, float b) {
  h2 r = __builtin_amdgcn_cvt_pkrtz(a, b);
  return __builtin_bit_cast(uint, r);
}
#if __has_builtin(__builtin_amdgcn_fdot2)
static __device__ __forceinline__ float dot2(uint a, uint b, float c) {
  return __builtin_amdgcn_fdot2(__builtin_bit_cast(h2, a), __builtin_bit_cast(h2, b), c, false);
}
#else
static __device__ __forceinline__ float dot2(uint a, uint b, float c) {
  h2 x = __builtin_bit_cast(h2, a), y = __builtin_bit_cast(h2, b);
  return c + (float)x.x * (float)y.x + (float)x.y * (float)y.y;
}
#endif
static __device__ __forceinline__ float h2f(ushort u) {
  return (float)__builtin_bit_cast(_Float16, u);
}

// ---------------- embedding + keep mask ----------------
__global__ void embed_k(const int* __restrict__ logs, const float* __restrict__ emb,
                        float* __restrict__ seqs) {
  int idx = blockIdx.x * 256 + threadIdx.x;
  int hcol = idx & (Hc - 1);
  int bl = idx >> 8;
  int tok = logs[bl];
  seqs[idx] = (tok == 0) ? 0.f : emb[tok * Hc + hcol];
}

// ---------------- layernorm over H=256, one block per row ----------------
__global__ void ln_k(const float* __restrict__ x, const float* __restrict__ g,
                     const float* __restrict__ bt, float* __restrict__ y) {
  int row = blockIdx.x;
  int t = threadIdx.x;
  float v = x[row * Hc + t];
  float a = v, sq = v * v;
  for (int o = 32; o; o >>= 1) { a += __shfl_down(a, o); sq += __shfl_down(sq, o); }
  __shared__ float s1[4], s2[4];
  __shared__ float mS, rS;
  int wave = t >> 6, lane = t & 63;
  if (lane == 0) { s1[wave] = a; s2[wave] = sq; }
  __syncthreads();
  if (t == 0) {
    float sum = s1[0] + s1[1] + s1[2] + s1[3];
    float ssq = s2[0] + s2[1] + s2[2] + s2[3];
    float m = sum * (1.f / Hc);
    float var = ssq * (1.f / Hc) - m * m;
    mS = m;
    rS = 1.f / sqrtf(var + 1e-8f);
  }
  __syncthreads();
  y[row * Hc + t] = (v - mS) * rS * g[t] + bt[t];
}

// ---------------- GEMM: out[M,N] = A[M,K] @ W[N,K]^T + bias ----
// FUSE: 0=+bias(f32) ; 1=relu(f32) ; 2=(+bias+X)*keep(f32)
//       5=packed f16 out ; 6=+pK[m%L] packed f16 ; 7=+pV[m%L] packed f16
template <int FUSE>
__global__ void gemm_k(const float* __restrict__ A, const float* __restrict__ W,
                       const float* __restrict__ bias, const float* __restrict__ X,
                       const int* __restrict__ logs, void* __restrict__ out) {
  __shared__ float As[32][33];
  __shared__ float Ws[32][33];
  int m0 = blockIdx.x * 32, n0 = blockIdx.y * 32;
  int t = threadIdx.x;
  int tx = t & 15, ty = t >> 4;
  int lr = t >> 3, lc = (t & 7) * 4;
  float c00 = 0.f, c01 = 0.f, c10 = 0.f, c11 = 0.f;
  for (int k0 = 0; k0 < Hc; k0 += 32) {
    float4 av = *(const float4*)&A[(m0 + lr) * Hc + k0 + lc];
    float4 wv = *(const float4*)&W[(n0 + lr) * Hc + k0 + lc];
    As[lr][lc] = av.x; As[lr][lc + 1] = av.y; As[lr][lc + 2] = av.z; As[lr][lc + 3] = av.w;
    Ws[lr][lc] = wv.x; Ws[lr][lc + 1] = wv.y; Ws[lr][lc + 2] = wv.z; Ws[lr][lc + 3] = wv.w;
    __syncthreads();
#pragma unroll
    for (int k = 0; k < 32; ++k) {
      float a0 = As[2 * ty][k], a1 = As[2 * ty + 1][k];
      float w0 = Ws[2 * tx][k], w1 = Ws[2 * tx + 1][k];
      c00 += a0 * w0; c01 += a0 * w1; c10 += a1 * w0; c11 += a1 * w1;
    }
    __syncthreads();
  }
  int m = m0 + 2 * ty, n = n0 + 2 * tx;
  float b0 = bias[n], b1v = bias[n + 1];
  float r00 = c00 + b0, r01 = c01 + b1v, r10 = c10 + b0, r11 = c11 + b1v;
  if (FUSE == 1) {
    r00 = fmaxf(r00, 0.f); r01 = fmaxf(r01, 0.f);
    r10 = fmaxf(r10, 0.f); r11 = fmaxf(r11, 0.f);
  } else if (FUSE == 2) {
    float k0m = (logs[m] != 0) ? 1.f : 0.f;
    float k1m = (logs[m + 1] != 0) ? 1.f : 0.f;
    r00 = (r00 + X[m * Hc + n]) * k0m;
    r01 = (r01 + X[m * Hc + n + 1]) * k0m;
    r10 = (r10 + X[(m + 1) * Hc + n]) * k1m;
    r11 = (r11 + X[(m + 1) * Hc + n + 1]) * k1m;
  } else if (FUSE == 6 || FUSE == 7) {
    int p0 = m % Lc, p1 = (m + 1) % Lc;
    r00 += X[p0 * Hc + n];     r01 += X[p0 * Hc + n + 1];
    r10 += X[p1 * Hc + n];     r11 += X[p1 * Hc + n + 1];
  }
  if (FUSE >= 5) {
    uint* o32 = (uint*)out;
    int m2 = m * (Hc / 2), n2 = n >> 1;
    o32[m2 + n2] = pkh2(r00, r01);
    o32[m2 + (Hc / 2) + n2] = pkh2(r10, r11);
  } else {
    float* of = (float*)out;
    of[m * Hc + n] = r00; of[m * Hc + n + 1] = r01;
    of[(m + 1) * Hc + n] = r10; of[(m + 1) * Hc + n + 1] = r11;
  }
}

// ---------------- attention scores + softmax -> A ----------------
// grid (NHc, Bc, QS2) = 512 blocks; block 256 (4 waves). f16 tables in LDS.
__global__ __launch_bounds__(256, 2)
void score_k(const uint* __restrict__ Q16, const uint* __restrict__ K16,
             const float* __restrict__ tK, const float* __restrict__ dK,
             const int* __restrict__ tm, const int* __restrict__ dm,
             const int* __restrict__ logs, float* __restrict__ A) {
  int h = blockIdx.x, b = blockIdx.y, qs = blockIdx.z;
  __shared__ uint tKs[257 * TROW];
  __shared__ uint dKs[257 * TROW];
  int t = threadIdx.x;
  for (int i = t; i < 257 * 16; i += 256) {
    int r = i >> 4, c4 = (i & 15) * 4;
    float4 tv = *(const float4*)&tK[r * Hc + h * HSc + c4];
    float4 dv = *(const float4*)&dK[r * Hc + h * HSc + c4];
    *(uint2*)&tKs[r * TROW + (c4 >> 1)] = make_uint2(pkh2(tv.x, tv.y), pkh2(tv.z, tv.w));
    *(uint2*)&dKs[r * TROW + (c4 >> 1)] = make_uint2(pkh2(dv.x, dv.y), pkh2(dv.z, dv.w));
  }
  __syncthreads();
  int w = t >> 6, lane = t & 63;
  int z = h * 4 + b;
  for (int j = w; qs + QS2 * j < Lc; j += 4) {
    int q = qs + QS2 * j;
    int m = b * Lc + q;
    int arow = __builtin_amdgcn_readfirstlane((z * Lc + q) * Lc);
    if (logs[m] == 0) {                     // pad query: A := 0 (zeroed by keep later anyway)
      for (int k = lane; k < Lc; k += 64) A[arow + k] = 0.f;
      continue;
    }
    const uint* Qr = Q16 + __builtin_amdgcn_readfirstlane(m * (Hc / 2) + h * (HSc / 2));
    uint qreg[32];
#pragma unroll
    for (int u = 0; u < 32; ++u) qreg[u] = Qr[u];     // wave-uniform -> SGPR
    const int* tmr = tm + __builtin_amdgcn_readfirstlane(m * Lc);
    const int* dmr = dm + __builtin_amdgcn_readfirstlane(m * Lc);
    int np = (q >> 6) + 1;
    float sv[4];
    float mx = neg_fill();
#pragma unroll
    for (int p = 0; p < 4; ++p) {
      sv[p] = neg_fill();
      if (p >= np) continue;
      int k = p * 64 + lane;
      int kc = (k <= q) ? k : q;
      int ti = tmr[kc], di = dmr[kc];
      const uint2* tr = (const uint2*)&tKs[ti * TROW];
      const uint2* dr = (const uint2*)&dKs[di * TROW];
      const uint4* Kr = (const uint4*)&K16[(b * Lc + kc) * (Hc / 2) + h * (HSc / 2)];
      float a0 = 0.f, a1 = 0.f;
#pragma unroll
      for (int u = 0; u < 8; ++u) {
        uint4 kv = Kr[u];
        uint2 tv0 = tr[2 * u], tv1 = tr[2 * u + 1];
        uint2 dv0 = dr[2 * u], dv1 = dr[2 * u + 1];
        a0 = dot2(qreg[4 * u + 0], kv.x, a0);  a1 = dot2(qreg[4 * u + 1], kv.y, a1);
        a0 = dot2(qreg[4 * u + 2], kv.z, a0);  a1 = dot2(qreg[4 * u + 3], kv.w, a1);
        a0 = dot2(qreg[4 * u + 0], tv0.x, a0); a1 = dot2(qreg[4 * u + 1], tv0.y, a1);
        a0 = dot2(qreg[4 * u + 2], tv1.x, a0); a1 = dot2(qreg[4 * u + 3], tv1.y, a1);
        a0 = dot2(qreg[4 * u + 0], dv0.x, a0); a1 = dot2(qreg[4 * u + 1], dv0.y, a1);
        a0 = dot2(qreg[4 * u + 2], dv1.x, a0); a1 = dot2(qreg[4 * u + 3], dv1.y, a1);
      }
      if (k <= q) sv[p] = (a0 + a1) * 0.125f;
      mx = fmaxf(mx, sv[p]);
    }
#pragma unroll
    for (int o = 32; o; o >>= 1) mx = fmaxf(mx, __shfl_xor(mx, o));
    float sum = 0.f;
    float ev[4];
#pragma unroll
    for (int p = 0; p < 4; ++p) {
      ev[p] = __expf(sv[p] - mx);
      sum += ev[p];
    }
#pragma unroll
    for (int o = 32; o; o >>= 1) sum += __shfl_xor(sum, o);
    float r = 1.f / sum;
#pragma unroll
    for (int p = 0; p < 4; ++p) {
      if (p >= np) continue;
      int k = p * 64 + lane;
      if (k < Lc) A[arow + k] = ev[p] * r;
    }
  }
}

// ---------------- attention output + residual ----------------
// grid (NHc, Bc, QS2); block 256. f16 tables in LDS; V packed f16 global.
__global__ __launch_bounds__(256, 2)
void out_k(const float* __restrict__ A, const ushort* __restrict__ V16,
           const float* __restrict__ tV, const float* __restrict__ dV,
           const int* __restrict__ tm, const int* __restrict__ dm,
           const int* __restrict__ logs,
           const float* __restrict__ Qn, float* __restrict__ seqs) {
  int h = blockIdx.x, b = blockIdx.y, qs = blockIdx.z;
  __shared__ ushort tVs[257 * 2 * TROW];
  __shared__ ushort dVs[257 * 2 * TROW];
  int t = threadIdx.x;
  {
    uint* tw = (uint*)tVs;
    uint* dw = (uint*)dVs;
    for (int i = t; i < 257 * 16; i += 256) {
      int r = i >> 4, c4 = (i & 15) * 4;
      float4 tv = *(const float4*)&tV[r * Hc + h * HSc + c4];
      float4 dv = *(const float4*)&dV[r * Hc + h * HSc + c4];
      *(uint2*)&tw[r * TROW + (c4 >> 1)] = make_uint2(pkh2(tv.x, tv.y), pkh2(tv.z, tv.w));
      *(uint2*)&dw[r * TROW + (c4 >> 1)] = make_uint2(pkh2(dv.x, dv.y), pkh2(dv.z, dv.w));
    }
  }
  __syncthreads();
  int w = t >> 6, lane = t & 63;
  int z = h * 4 + b;
  for (int j = w; qs + QS2 * j < Lc; j += 4) {
    int q = qs + QS2 * j;
    int m = b * Lc + q;
    int oi = m * Hc + h * HSc + lane;
    if (logs[m] == 0) { seqs[oi] = Qn[oi]; continue; }
    const float* Ar = A + __builtin_amdgcn_readfirstlane((z * Lc + q) * Lc);
    const int* tmr = tm + __builtin_amdgcn_readfirstlane(m * Lc);
    const int* dmr = dm + __builtin_amdgcn_readfirstlane(m * Lc);
    const ushort* Vb = V16 + __builtin_amdgcn_readfirstlane(b * Lc * Hc + h * HSc) + lane;
    float acc0 = 0.f, acc1 = 0.f;
    int k = 0;
    for (; k + 1 <= q; k += 2) {
      float av0 = Ar[k], av1 = Ar[k + 1];
      int t0 = tmr[k], d0 = dmr[k];
      int t1 = tmr[k + 1], d1 = dmr[k + 1];
      float v0 = h2f(Vb[k * Hc]);
      float v1 = h2f(Vb[(k + 1) * Hc]);
      float tf0 = h2f(tVs[t0 * 68 + lane]);
      float df0 = h2f(dVs[d0 * 68 + lane]);
      float tf1 = h2f(tVs[t1 * 68 + lane]);
      float df1 = h2f(dVs[d1 * 68 + lane]);
      acc0 = fmaf(av0, v0 + tf0 + df0, acc0);
      acc1 = fmaf(av1, v1 + tf1 + df1, acc1);
    }
    if (k <= q) {
      float av0 = Ar[k];
      int t0 = tmr[k], d0 = dmr[k];
      float v0 = h2f(Vb[k * Hc]);
      float tf0 = h2f(tVs[t0 * 68 + lane]);
      float df0 = h2f(dVs[d0 * 68 + lane]);
      acc0 = fmaf(av0, v0 + tf0 + df0, acc0);
    }
    seqs[oi] = Qn[oi] + acc0 + acc1;
  }
}

extern "C" void kernel_launch(void* const* d_in, const int* in_sizes, int n_in,
                              void* d_out, int out_size, void* d_ws, size_t ws_size,
                              hipStream_t stream) {
  const int* logs = (const int*)d_in[0];
  const int* tm   = (const int*)d_in[1];
  const int* dm   = (const int*)d_in[2];
  const float* item = (const float*)d_in[3];
  const float* pK = (const float*)d_in[4];
  const float* pV = (const float*)d_in[5];
  const float* tK = (const float*)d_in[6];
  const float* tV = (const float*)d_in[7];
  const float* dK = (const float*)d_in[8];
  const float* dV = (const float*)d_in[9];
  const float* ln1_g = (const float*)d_in[10];
  const float* ln1_b = (const float*)d_in[11];
  const float* Wq = (const float*)d_in[12];
  const float* bq = (const float*)d_in[13];
  const float* Wk = (const float*)d_in[14];
  const float* bk = (const float*)d_in[15];
  const float* Wv = (const float*)d_in[16];
  const float* bv = (const float*)d_in[17];
  const float* ln2_g = (const float*)d_in[18];
  const float* ln2_b = (const float*)d_in[19];
  const float* W1 = (const float*)d_in[20];
  const float* b1 = (const float*)d_in[21];
  const float* W2 = (const float*)d_in[22];
  const float* b2 = (const float*)d_in[23];
  const float* lnf_g = (const float*)d_in[24];
  const float* lnf_b = (const float*)d_in[25];

  const int NROW = Mtot * Hc;          // 204800 floats
  float* ws = (float*)d_ws;
  float* sSeqs = ws + 0 * NROW;
  float* sQn   = ws + 1 * NROW;
  float* sX    = ws + 2 * NROW;
  float* sH    = ws + 3 * NROW;
  float* Abuf  = ws + 4 * NROW;               // 16*200*200 = 640000 floats
  uint*  Q16   = (uint*)(Abuf + 16 * Lc * Lc);
  uint*  K16   = Q16 + Mtot * (Hc / 2);
  uint*  V16   = K16 + Mtot * (Hc / 2);

  embed_k<<<NROW / 256, 256, 0, stream>>>(logs, item, sSeqs);

  dim3 gg(Mtot / 32, Hc / 32);
  dim3 ga(NHc, Bc, QS2);               // 512 blocks
  for (int i = 0; i < NBc; ++i) {
    ln_k<<<Mtot, Hc, 0, stream>>>(sSeqs, ln1_g + i * Hc, ln1_b + i * Hc, sQn);
    gemm_k<5><<<gg, 256, 0, stream>>>(sQn,   Wq + i * Hc * Hc, bq + i * Hc, nullptr, nullptr, Q16);
    gemm_k<6><<<gg, 256, 0, stream>>>(sSeqs, Wk + i * Hc * Hc, bk + i * Hc, pK, nullptr, K16);
    gemm_k<7><<<gg, 256, 0, stream>>>(sSeqs, Wv + i * Hc * Hc, bv + i * Hc, pV, nullptr, V16);
    score_k<<<ga, 256, 0, stream>>>(Q16, K16, tK, dK, tm, dm, logs, Abuf);
    out_k<<<ga, 256, 0, stream>>>(Abuf, (const ushort*)V16, tV, dV, tm, dm, logs, sQn, sSeqs);
    ln_k<<<Mtot, Hc, 0, stream>>>(sSeqs, ln2_g + i * Hc, ln2_b + i * Hc, sX);
    gemm_k<1><<<gg, 256, 0, stream>>>(sX, W1 + i * Hc * Hc, b1 + i * Hc, nullptr, nullptr, sH);
    gemm_k<2><<<gg, 256, 0, stream>>>(sH, W2 + i * Hc * Hc, b2 + i * Hc, sX, logs, sSeqs);
  }
  ln_k<<<Mtot, Hc, 0, stream>>>(sSeqs, lnf_g, lnf_b, (float*)d_out);
}

// Round 6
// 180.084 us; speedup vs baseline: 2.8430x; 1.2762x over previous
//
#include <hip/hip_runtime.h>
#include <math.h>

typedef __fp16 h2 __attribute__((ext_vector_type(2)));

#define Bc 4
#define Lc 200
#define Hc 256
#define NHc 4
#define HSc 64
#define NBc 2
#define Mtot (Bc*Lc)   // 800
#define TROW 34        // LDS table row stride in u32 (68 halfs = 136B, odd uint2 stride)

static __device__ __forceinline__ float neg_fill() { return -4294967295.0f; }

static __device__ __forceinline__ uint pkh2(float a, float b) {
  h2 r = __builtin_amdgcn_cvt_pkrtz(a, b);
  return __builtin_bit_cast(uint, r);
}
#if __has_builtin(__builtin_amdgcn_fdot2)
static __device__ __forceinline__ float dot2(uint a, uint b, float c) {
  return __builtin_amdgcn_fdot2(__builtin_bit_cast(h2, a), __builtin_bit_cast(h2, b), c, false);
}
#else
static __device__ __forceinline__ float dot2(uint a, uint b, float c) {
  h2 x = __builtin_bit_cast(h2, a), y = __builtin_bit_cast(h2, b);
  return c + (float)x.x * (float)y.x + (float)x.y * (float)y.y;
}
#endif
static __device__ __forceinline__ float h2f(ushort u) {
  return (float)__builtin_bit_cast(_Float16, u);
}

// ---------------- embedding + keep mask ----------------
__global__ void embed_k(const int* __restrict__ logs, const float* __restrict__ emb,
                        float* __restrict__ seqs) {
  int idx = blockIdx.x * 256 + threadIdx.x;
  int hcol = idx & (Hc - 1);
  int bl = idx >> 8;
  int tok = logs[bl];
  seqs[idx] = (tok == 0) ? 0.f : emb[tok * Hc + hcol];
}

// ---------------- layernorm over H=256, one block per row ----------------
__global__ void ln_k(const float* __restrict__ x, const float* __restrict__ g,
                     const float* __restrict__ bt, float* __restrict__ y) {
  int row = blockIdx.x;
  int t = threadIdx.x;
  float v = x[row * Hc + t];
  float a = v, sq = v * v;
  for (int o = 32; o; o >>= 1) { a += __shfl_down(a, o); sq += __shfl_down(sq, o); }
  __shared__ float s1[4], s2[4];
  __shared__ float mS, rS;
  int wave = t >> 6, lane = t & 63;
  if (lane == 0) { s1[wave] = a; s2[wave] = sq; }
  __syncthreads();
  if (t == 0) {
    float sum = s1[0] + s1[1] + s1[2] + s1[3];
    float ssq = s2[0] + s2[1] + s2[2] + s2[3];
    float m = sum * (1.f / Hc);
    float var = ssq * (1.f / Hc) - m * m;
    mS = m;
    rS = 1.f / sqrtf(var + 1e-8f);
  }
  __syncthreads();
  y[row * Hc + t] = (v - mS) * rS * g[t] + bt[t];
}

// ---------------- GEMM: out[M,N] = A[M,K] @ W[N,K]^T + bias ----
// FUSE: 0=+bias(f32) ; 1=relu(f32) ; 2=(+bias+X)*keep(f32)
//       5=packed f16 out ; 6=+pK[m%L] packed f16 ; 7=+pV[m%L] packed f16
template <int FUSE>
__global__ void gemm_k(const float* __restrict__ A, const float* __restrict__ W,
                       const float* __restrict__ bias, const float* __restrict__ X,
                       const int* __restrict__ logs, void* __restrict__ out) {
  __shared__ float As[32][33];
  __shared__ float Ws[32][33];
  int m0 = blockIdx.x * 32, n0 = blockIdx.y * 32;
  int t = threadIdx.x;
  int tx = t & 15, ty = t >> 4;
  int lr = t >> 3, lc = (t & 7) * 4;
  float c00 = 0.f, c01 = 0.f, c10 = 0.f, c11 = 0.f;
  for (int k0 = 0; k0 < Hc; k0 += 32) {
    float4 av = *(const float4*)&A[(m0 + lr) * Hc + k0 + lc];
    float4 wv = *(const float4*)&W[(n0 + lr) * Hc + k0 + lc];
    As[lr][lc] = av.x; As[lr][lc + 1] = av.y; As[lr][lc + 2] = av.z; As[lr][lc + 3] = av.w;
    Ws[lr][lc] = wv.x; Ws[lr][lc + 1] = wv.y; Ws[lr][lc + 2] = wv.z; Ws[lr][lc + 3] = wv.w;
    __syncthreads();
#pragma unroll
    for (int k = 0; k < 32; ++k) {
      float a0 = As[2 * ty][k], a1 = As[2 * ty + 1][k];
      float w0 = Ws[2 * tx][k], w1 = Ws[2 * tx + 1][k];
      c00 += a0 * w0; c01 += a0 * w1; c10 += a1 * w0; c11 += a1 * w1;
    }
    __syncthreads();
  }
  int m = m0 + 2 * ty, n = n0 + 2 * tx;
  float b0 = bias[n], b1v = bias[n + 1];
  float r00 = c00 + b0, r01 = c01 + b1v, r10 = c10 + b0, r11 = c11 + b1v;
  if (FUSE == 1) {
    r00 = fmaxf(r00, 0.f); r01 = fmaxf(r01, 0.f);
    r10 = fmaxf(r10, 0.f); r11 = fmaxf(r11, 0.f);
  } else if (FUSE == 2) {
    float k0m = (logs[m] != 0) ? 1.f : 0.f;
    float k1m = (logs[m + 1] != 0) ? 1.f : 0.f;
    r00 = (r00 + X[m * Hc + n]) * k0m;
    r01 = (r01 + X[m * Hc + n + 1]) * k0m;
    r10 = (r10 + X[(m + 1) * Hc + n]) * k1m;
    r11 = (r11 + X[(m + 1) * Hc + n + 1]) * k1m;
  } else if (FUSE == 6 || FUSE == 7) {
    int p0 = m % Lc, p1 = (m + 1) % Lc;
    r00 += X[p0 * Hc + n];     r01 += X[p0 * Hc + n + 1];
    r10 += X[p1 * Hc + n];     r11 += X[p1 * Hc + n + 1];
  }
  if (FUSE >= 5) {
    uint* o32 = (uint*)out;
    int m2 = m * (Hc / 2), n2 = n >> 1;
    o32[m2 + n2] = pkh2(r00, r01);
    o32[m2 + (Hc / 2) + n2] = pkh2(r10, r11);
  } else {
    float* of = (float*)out;
    of[m * Hc + n] = r00; of[m * Hc + n + 1] = r01;
    of[(m + 1) * Hc + n] = r10; of[(m + 1) * Hc + n + 1] = r11;
  }
}

// ---------------- attention scores + softmax -> A ----------------
// grid (NHc, Bc, 16) = 256 blocks; block 1024 (16 waves), one q-row per wave.
__global__ __launch_bounds__(1024, 4)
void score_k(const uint* __restrict__ Q16, const uint* __restrict__ K16,
             const float* __restrict__ tK, const float* __restrict__ dK,
             const int* __restrict__ tm, const int* __restrict__ dm,
             const int* __restrict__ logs, float* __restrict__ A) {
  int h = blockIdx.x, b = blockIdx.y, bz = blockIdx.z;
  __shared__ uint tKs[257 * TROW];
  __shared__ uint dKs[257 * TROW];
  int t = threadIdx.x;
  for (int i = t; i < 257 * 16; i += 1024) {
    int r = i >> 4, c4 = (i & 15) * 4;
    float4 tv = *(const float4*)&tK[r * Hc + h * HSc + c4];
    float4 dv = *(const float4*)&dK[r * Hc + h * HSc + c4];
    *(uint2*)&tKs[r * TROW + (c4 >> 1)] = make_uint2(pkh2(tv.x, tv.y), pkh2(tv.z, tv.w));
    *(uint2*)&dKs[r * TROW + (c4 >> 1)] = make_uint2(pkh2(dv.x, dv.y), pkh2(dv.z, dv.w));
  }
  __syncthreads();
  int wave = t >> 6, lane = t & 63;
  int z = h * 4 + b;
  int q = wave * 16 + bz;            // balanced q spread per block
  if (q >= Lc) return;
  int m = b * Lc + q;
  int arow = __builtin_amdgcn_readfirstlane((z * Lc + q) * Lc);
  if (logs[m] == 0) {                // pad query: A := 0
    for (int k = lane; k < Lc; k += 64) A[arow + k] = 0.f;
    return;
  }
  const uint* Qr = Q16 + __builtin_amdgcn_readfirstlane(m * (Hc / 2) + h * (HSc / 2));
  uint qreg[32];
#pragma unroll
  for (int u = 0; u < 32; ++u) qreg[u] = Qr[u];      // wave-uniform -> SGPR
  const int* tmr = tm + __builtin_amdgcn_readfirstlane(m * Lc);
  const int* dmr = dm + __builtin_amdgcn_readfirstlane(m * Lc);
  int np = (q >> 6) + 1;
  float sv[4];
  float mx = neg_fill();
#pragma unroll
  for (int p = 0; p < 4; ++p) {
    sv[p] = neg_fill();
    if (p >= np) continue;
    int k = p * 64 + lane;
    int kc = (k <= q) ? k : q;
    int ti = tmr[kc], di = dmr[kc];
    const uint2* tr = (const uint2*)&tKs[ti * TROW];
    const uint2* dr = (const uint2*)&dKs[di * TROW];
    const uint4* Kr = (const uint4*)&K16[(b * Lc + kc) * (Hc / 2) + h * (HSc / 2)];
    float a0 = 0.f, a1 = 0.f;
#pragma unroll
    for (int u = 0; u < 8; ++u) {
      uint4 kv = Kr[u];
      uint2 tv0 = tr[2 * u], tv1 = tr[2 * u + 1];
      uint2 dv0 = dr[2 * u], dv1 = dr[2 * u + 1];
      a0 = dot2(qreg[4 * u + 0], kv.x, a0);  a1 = dot2(qreg[4 * u + 1], kv.y, a1);
      a0 = dot2(qreg[4 * u + 2], kv.z, a0);  a1 = dot2(qreg[4 * u + 3], kv.w, a1);
      a0 = dot2(qreg[4 * u + 0], tv0.x, a0); a1 = dot2(qreg[4 * u + 1], tv0.y, a1);
      a0 = dot2(qreg[4 * u + 2], tv1.x, a0); a1 = dot2(qreg[4 * u + 3], tv1.y, a1);
      a0 = dot2(qreg[4 * u + 0], dv0.x, a0); a1 = dot2(qreg[4 * u + 1], dv0.y, a1);
      a0 = dot2(qreg[4 * u + 2], dv1.x, a0); a1 = dot2(qreg[4 * u + 3], dv1.y, a1);
    }
    if (k <= q) sv[p] = (a0 + a1) * 0.125f;
    mx = fmaxf(mx, sv[p]);
  }
#pragma unroll
  for (int o = 32; o; o >>= 1) mx = fmaxf(mx, __shfl_xor(mx, o));
  float sum = 0.f;
  float ev[4];
#pragma unroll
  for (int p = 0; p < 4; ++p) {
    ev[p] = __expf(sv[p] - mx);
    sum += ev[p];
  }
#pragma unroll
  for (int o = 32; o; o >>= 1) sum += __shfl_xor(sum, o);
  float r = 1.f / sum;
#pragma unroll
  for (int p = 0; p < 4; ++p) {
    if (p >= np) continue;
    int k = p * 64 + lane;
    if (k < Lc) A[arow + k] = ev[p] * r;
  }
}

// ---------------- attention output + residual ----------------
// grid (NHc, Bc, 16); block 1024 (16 waves), one q-row per wave, unroll-8 k.
__global__ __launch_bounds__(1024, 4)
void out_k(const float* __restrict__ A, const ushort* __restrict__ V16,
           const float* __restrict__ tV, const float* __restrict__ dV,
           const int* __restrict__ tm, const int* __restrict__ dm,
           const int* __restrict__ logs,
           const float* __restrict__ Qn, float* __restrict__ seqs) {
  int h = blockIdx.x, b = blockIdx.y, bz = blockIdx.z;
  __shared__ ushort tVs[257 * 2 * TROW];
  __shared__ ushort dVs[257 * 2 * TROW];
  int t = threadIdx.x;
  {
    uint* tw = (uint*)tVs;
    uint* dw = (uint*)dVs;
    for (int i = t; i < 257 * 16; i += 1024) {
      int r = i >> 4, c4 = (i & 15) * 4;
      float4 tv = *(const float4*)&tV[r * Hc + h * HSc + c4];
      float4 dv = *(const float4*)&dV[r * Hc + h * HSc + c4];
      *(uint2*)&tw[r * TROW + (c4 >> 1)] = make_uint2(pkh2(tv.x, tv.y), pkh2(tv.z, tv.w));
      *(uint2*)&dw[r * TROW + (c4 >> 1)] = make_uint2(pkh2(dv.x, dv.y), pkh2(dv.z, dv.w));
    }
  }
  __syncthreads();
  int wave = t >> 6, lane = t & 63;
  int z = h * 4 + b;
  int q = wave * 16 + bz;
  if (q >= Lc) return;
  int m = b * Lc + q;
  int oi = m * Hc + h * HSc + lane;
  if (logs[m] == 0) { seqs[oi] = Qn[oi]; return; }
  const float* Ar = A + __builtin_amdgcn_readfirstlane((z * Lc + q) * Lc);
  const int* tmr = tm + __builtin_amdgcn_readfirstlane(m * Lc);
  const int* dmr = dm + __builtin_amdgcn_readfirstlane(m * Lc);
  const ushort* Vb = V16 + __builtin_amdgcn_readfirstlane(b * Lc * Hc + h * HSc) + lane;
  float acc0 = 0.f, acc1 = 0.f, acc2 = 0.f, acc3 = 0.f;
  int k0 = 0;
  for (; k0 + 7 <= q; k0 += 8) {
    float a_[8]; int ti_[8], di_[8];
#pragma unroll
    for (int u = 0; u < 8; ++u) { a_[u] = Ar[k0 + u]; ti_[u] = tmr[k0 + u]; di_[u] = dmr[k0 + u]; }
    float v_[8], tf_[8], df_[8];
#pragma unroll
    for (int u = 0; u < 8; ++u) {
      v_[u] = h2f(Vb[(k0 + u) * Hc]);
      tf_[u] = h2f(tVs[ti_[u] * 68 + lane]);
      df_[u] = h2f(dVs[di_[u] * 68 + lane]);
    }
    acc0 = fmaf(a_[0], v_[0] + tf_[0] + df_[0], acc0);
    acc1 = fmaf(a_[1], v_[1] + tf_[1] + df_[1], acc1);
    acc2 = fmaf(a_[2], v_[2] + tf_[2] + df_[2], acc2);
    acc3 = fmaf(a_[3], v_[3] + tf_[3] + df_[3], acc3);
    acc0 = fmaf(a_[4], v_[4] + tf_[4] + df_[4], acc0);
    acc1 = fmaf(a_[5], v_[5] + tf_[5] + df_[5], acc1);
    acc2 = fmaf(a_[6], v_[6] + tf_[6] + df_[6], acc2);
    acc3 = fmaf(a_[7], v_[7] + tf_[7] + df_[7], acc3);
  }
  for (; k0 <= q; ++k0) {
    float av = Ar[k0];
    int ti = tmr[k0], di = dmr[k0];
    float vv = h2f(Vb[k0 * Hc]);
    float tf = h2f(tVs[ti * 68 + lane]);
    float df = h2f(dVs[di * 68 + lane]);
    acc0 = fmaf(av, vv + tf + df, acc0);
  }
  seqs[oi] = Qn[oi] + (acc0 + acc1) + (acc2 + acc3);
}

extern "C" void kernel_launch(void* const* d_in, const int* in_sizes, int n_in,
                              void* d_out, int out_size, void* d_ws, size_t ws_size,
                              hipStream_t stream) {
  const int* logs = (const int*)d_in[0];
  const int* tm   = (const int*)d_in[1];
  const int* dm   = (const int*)d_in[2];
  const float* item = (const float*)d_in[3];
  const float* pK = (const float*)d_in[4];
  const float* pV = (const float*)d_in[5];
  const float* tK = (const float*)d_in[6];
  const float* tV = (const float*)d_in[7];
  const float* dK = (const float*)d_in[8];
  const float* dV = (const float*)d_in[9];
  const float* ln1_g = (const float*)d_in[10];
  const float* ln1_b = (const float*)d_in[11];
  const float* Wq = (const float*)d_in[12];
  const float* bq = (const float*)d_in[13];
  const float* Wk = (const float*)d_in[14];
  const float* bk = (const float*)d_in[15];
  const float* Wv = (const float*)d_in[16];
  const float* bv = (const float*)d_in[17];
  const float* ln2_g = (const float*)d_in[18];
  const float* ln2_b = (const float*)d_in[19];
  const float* W1 = (const float*)d_in[20];
  const float* b1 = (const float*)d_in[21];
  const float* W2 = (const float*)d_in[22];
  const float* b2 = (const float*)d_in[23];
  const float* lnf_g = (const float*)d_in[24];
  const float* lnf_b = (const float*)d_in[25];

  const int NROW = Mtot * Hc;          // 204800 floats
  float* ws = (float*)d_ws;
  float* sSeqs = ws + 0 * NROW;
  float* sQn   = ws + 1 * NROW;
  float* sX    = ws + 2 * NROW;
  float* sH    = ws + 3 * NROW;
  float* Abuf  = ws + 4 * NROW;               // 16*200*200 = 640000 floats
  uint*  Q16   = (uint*)(Abuf + 16 * Lc * Lc);
  uint*  K16   = Q16 + Mtot * (Hc / 2);
  uint*  V16   = K16 + Mtot * (Hc / 2);

  embed_k<<<NROW / 256, 256, 0, stream>>>(logs, item, sSeqs);

  dim3 gg(Mtot / 32, Hc / 32);
  dim3 ga(NHc, Bc, 16);                // 256 blocks x 1024 threads
  for (int i = 0; i < NBc; ++i) {
    ln_k<<<Mtot, Hc, 0, stream>>>(sSeqs, ln1_g + i * Hc, ln1_b + i * Hc, sQn);
    gemm_k<5><<<gg, 256, 0, stream>>>(sQn,   Wq + i * Hc * Hc, bq + i * Hc, nullptr, nullptr, Q16);
    gemm_k<6><<<gg, 256, 0, stream>>>(sSeqs, Wk + i * Hc * Hc, bk + i * Hc, pK, nullptr, K16);
    gemm_k<7><<<gg, 256, 0, stream>>>(sSeqs, Wv + i * Hc * Hc, bv + i * Hc, pV, nullptr, V16);
    score_k<<<ga, 1024, 0, stream>>>(Q16, K16, tK, dK, tm, dm, logs, Abuf);
    out_k<<<ga, 1024, 0, stream>>>(Abuf, (const ushort*)V16, tV, dV, tm, dm, logs, sQn, sSeqs);
    ln_k<<<Mtot, Hc, 0, stream>>>(sSeqs, ln2_g + i * Hc, ln2_b + i * Hc, sX);
    gemm_k<1><<<gg, 256, 0, stream>>>(sX, W1 + i * Hc * Hc, b1 + i * Hc, nullptr, nullptr, sH);
    gemm_k<2><<<gg, 256, 0, stream>>>(sH, W2 + i * Hc * Hc, b2 + i * Hc, sX, logs, sSeqs);
  }
  ln_k<<<Mtot, Hc, 0, stream>>>(sSeqs, lnf_g, lnf_b, (float*)d_out);
}

// Round 7
// 118.574 us; speedup vs baseline: 4.3178x; 1.5188x over previous
//
#include <hip/hip_runtime.h>
#include <math.h>

typedef __fp16 h2 __attribute__((ext_vector_type(2)));
typedef __fp16 f16x8 __attribute__((ext_vector_type(8)));
typedef float f32x4 __attribute__((ext_vector_type(4)));

#define Bc 4
#define Lc 200
#define Hc 256
#define NHc 4
#define HSc 64
#define NBc 2
#define Mtot (Bc*Lc)   // 800
#define TROW 34        // LDS table row stride in u32 (68 halfs = 136B)
#define LDH 264        // mm LDS row stride in halves (528B, 16B-aligned, 4-bank skew)

static __device__ __forceinline__ float neg_fill() { return -4294967295.0f; }
static __device__ __forceinline__ int rl(int x) { return __builtin_amdgcn_readfirstlane(x); }

static __device__ __forceinline__ uint pkh2(float a, float b) {
  h2 r = __builtin_amdgcn_cvt_pkrtz(a, b);
  return __builtin_bit_cast(uint, r);
}
#if __has_builtin(__builtin_amdgcn_fdot2)
static __device__ __forceinline__ float dot2(uint a, uint b, float c) {
  return __builtin_amdgcn_fdot2(__builtin_bit_cast(h2, a), __builtin_bit_cast(h2, b), c, false);
}
#else
static __device__ __forceinline__ float dot2(uint a, uint b, float c) {
  h2 x = __builtin_bit_cast(h2, a), y = __builtin_bit_cast(h2, b);
  return c + (float)x.x * (float)y.x + (float)x.y * (float)y.y;
}
#endif
static __device__ __forceinline__ float h2f(ushort u) {
  return (float)__builtin_bit_cast(_Float16, u);
}

// ---------------- embedding + keep mask ----------------
__global__ void embed_k(const int* __restrict__ logs, const float* __restrict__ emb,
                        float* __restrict__ seqs) {
  int idx = blockIdx.x * 256 + threadIdx.x;
  int hcol = idx & (Hc - 1);
  int bl = idx >> 8;
  int tok = logs[bl];
  seqs[idx] = (tok == 0) ? 0.f : emb[tok * Hc + hcol];
}

// ---------------- layernorm over H=256, one block per row ----------------
__global__ void ln_k(const float* __restrict__ x, const float* __restrict__ g,
                     const float* __restrict__ bt, float* __restrict__ y) {
  int row = blockIdx.x;
  int t = threadIdx.x;
  float v = x[row * Hc + t];
  float a = v, sq = v * v;
  for (int o = 32; o; o >>= 1) { a += __shfl_down(a, o); sq += __shfl_down(sq, o); }
  __shared__ float s1[4], s2[4];
  __shared__ float mS, rS;
  int wave = t >> 6, lane = t & 63;
  if (lane == 0) { s1[wave] = a; s2[wave] = sq; }
  __syncthreads();
  if (t == 0) {
    float sum = s1[0] + s1[1] + s1[2] + s1[3];
    float ssq = s2[0] + s2[1] + s2[2] + s2[3];
    float m = sum * (1.f / Hc);
    float var = ssq * (1.f / Hc) - m * m;
    mS = m;
    rS = 1.f / sqrtf(var + 1e-8f);
  }
  __syncthreads();
  y[row * Hc + t] = (v - mS) * rS * g[t] + bt[t];
}

// ---------------- MFMA GEMM: out[M,N] = A[M,K] @ W[N,K]^T (+epilogue) ----
// BM=16, BN=64, 256 threads (4 waves, 1 frag each), K=256 staged as f16.
// MODE 0: QKV fused (n-region selects A/W/bias/out; f16 out; +pK/pV for K/V)
// MODE 1: relu, f32 out
// MODE 2: (+bias + X) * keep, f32 out
template <int MODE>
__global__ __launch_bounds__(256)
void mm_k(const float* __restrict__ A0, const float* __restrict__ A1,
          const float* __restrict__ W0, const float* __restrict__ W1p,
          const float* __restrict__ W2p,
          const float* __restrict__ b0, const float* __restrict__ b1p,
          const float* __restrict__ b2p,
          const float* __restrict__ pK, const float* __restrict__ pV,
          const float* __restrict__ X, const int* __restrict__ logs,
          void* __restrict__ o0, void* __restrict__ o1, void* __restrict__ o2) {
  __shared__ __fp16 Al[16][LDH];
  __shared__ __fp16 Wl[64][LDH];
  int m0 = blockIdx.x * 16;
  int n0g = blockIdx.y * 64;
  int region = n0g >> 8, nloc = n0g & 255;
  const float* Asrc;
  const float* Wsrc;
  const float* bias;
  if (MODE == 0) {
    Asrc = (region == 0) ? A0 : A1;
    Wsrc = (region == 0) ? W0 : (region == 1 ? W1p : W2p);
    bias = (region == 0) ? b0 : (region == 1 ? b1p : b2p);
  } else {
    Asrc = A0; Wsrc = W0; bias = b0;
  }
  int t = threadIdx.x;
  for (int i = t; i < 16 * 64; i += 256) {
    int r = i >> 6, c = (i & 63) * 4;
    float4 v = *(const float4*)&Asrc[(m0 + r) * Hc + c];
    *(h2*)&Al[r][c] = __builtin_amdgcn_cvt_pkrtz(v.x, v.y);
    *(h2*)&Al[r][c + 2] = __builtin_amdgcn_cvt_pkrtz(v.z, v.w);
  }
  for (int i = t; i < 64 * 64; i += 256) {
    int r = i >> 6, c = (i & 63) * 4;
    float4 v = *(const float4*)&Wsrc[(nloc + r) * Hc + c];
    *(h2*)&Wl[r][c] = __builtin_amdgcn_cvt_pkrtz(v.x, v.y);
    *(h2*)&Wl[r][c + 2] = __builtin_amdgcn_cvt_pkrtz(v.z, v.w);
  }
  __syncthreads();
  int wave = t >> 6, lane = t & 63;
  int row = lane & 15, kg = lane >> 4;
  int bn = wave * 16 + row;
  f32x4 acc = {0.f, 0.f, 0.f, 0.f};
#pragma unroll
  for (int k0 = 0; k0 < Hc; k0 += 32) {
    int kk = k0 + kg * 8;
    f16x8 a = *(const f16x8*)&Al[row][kk];
    f16x8 bb = *(const f16x8*)&Wl[bn][kk];
    acc = __builtin_amdgcn_mfma_f32_16x16x32_f16(a, bb, acc, 0, 0, 0);
  }
  int coln = nloc + wave * 16 + row;   // row == lane&15 == output col index
#pragma unroll
  for (int r = 0; r < 4; ++r) {
    int m = m0 + kg * 4 + r;
    float v = acc[r] + bias[coln];
    if (MODE == 0) {
      if (region) {
        const float* pT = (region == 1) ? pK : pV;
        v += pT[(m % Lc) * Hc + coln];
      }
      ushort* op = (ushort*)(region == 0 ? o0 : (region == 1 ? o1 : o2));
      op[m * Hc + coln] = __builtin_bit_cast(ushort, (_Float16)v);
    } else if (MODE == 1) {
      ((float*)o0)[m * Hc + coln] = fmaxf(v, 0.f);
    } else {
      float keep = (logs[m] != 0) ? 1.f : 0.f;
      ((float*)o0)[m * Hc + coln] = (v + X[m * Hc + coln]) * keep;
    }
  }
}

// ---------------- fused attention: scores + softmax + output + residual ------
// grid (NHc, Bc, 16) = 256 blocks; block 1024 (16 waves), one q-row per wave.
// All four f16 tables staged in LDS; A row shared per-wave via LDS.
__global__ __launch_bounds__(1024, 4)
void attn_k(const uint* __restrict__ Q16, const uint* __restrict__ K16,
            const ushort* __restrict__ V16,
            const float* __restrict__ tK, const float* __restrict__ dK,
            const float* __restrict__ tV, const float* __restrict__ dV,
            const int* __restrict__ tm, const int* __restrict__ dm,
            const int* __restrict__ logs,
            const float* __restrict__ Qn, float* __restrict__ seqs) {
  int h = blockIdx.x, b = blockIdx.y, bz = blockIdx.z;
  __shared__ uint tKs[257 * TROW];
  __shared__ uint dKs[257 * TROW];
  __shared__ uint tVs[257 * TROW];
  __shared__ uint dVs[257 * TROW];
  __shared__ float sArow[16][204];
  int t = threadIdx.x;
  for (int i = t; i < 257 * 16; i += 1024) {
    int r = i >> 4, c4 = (i & 15) * 4;
    float4 a = *(const float4*)&tK[r * Hc + h * HSc + c4];
    float4 c = *(const float4*)&dK[r * Hc + h * HSc + c4];
    float4 e = *(const float4*)&tV[r * Hc + h * HSc + c4];
    float4 f = *(const float4*)&dV[r * Hc + h * HSc + c4];
    *(uint2*)&tKs[r * TROW + (c4 >> 1)] = make_uint2(pkh2(a.x, a.y), pkh2(a.z, a.w));
    *(uint2*)&dKs[r * TROW + (c4 >> 1)] = make_uint2(pkh2(c.x, c.y), pkh2(c.z, c.w));
    *(uint2*)&tVs[r * TROW + (c4 >> 1)] = make_uint2(pkh2(e.x, e.y), pkh2(e.z, e.w));
    *(uint2*)&dVs[r * TROW + (c4 >> 1)] = make_uint2(pkh2(f.x, f.y), pkh2(f.z, f.w));
  }
  __syncthreads();
  int wave = t >> 6, lane = t & 63;
  int z = h * 4 + b;
  int q = wave * 16 + bz;
  if (q >= Lc) return;
  int m = b * Lc + q;
  int oi = m * Hc + h * HSc + lane;
  if (logs[m] == 0) { seqs[oi] = Qn[oi]; return; }
  const int* tmr = tm + rl(m * Lc);
  const int* dmr = dm + rl(m * Lc);
  // ---- score phase ----
  const uint* Qr = Q16 + rl(m * (Hc / 2) + h * (HSc / 2));
  uint qreg[32];
#pragma unroll
  for (int u = 0; u < 32; ++u) qreg[u] = Qr[u];
  int np = (q >> 6) + 1;
  float sv[4];
  float mx = neg_fill();
#pragma unroll
  for (int p = 0; p < 4; ++p) {
    sv[p] = neg_fill();
    if (p >= np) continue;
    int k = p * 64 + lane;
    int kc = (k <= q) ? k : q;
    int ti = tmr[kc], di = dmr[kc];
    const uint2* tr = (const uint2*)&tKs[ti * TROW];
    const uint2* dr = (const uint2*)&dKs[di * TROW];
    const uint4* Kr = (const uint4*)&K16[(b * Lc + kc) * (Hc / 2) + h * (HSc / 2)];
    float a0 = 0.f, a1 = 0.f;
#pragma unroll
    for (int u = 0; u < 8; ++u) {
      uint4 kv = Kr[u];
      uint2 tv0 = tr[2 * u], tv1 = tr[2 * u + 1];
      uint2 dv0 = dr[2 * u], dv1 = dr[2 * u + 1];
      a0 = dot2(qreg[4 * u + 0], kv.x, a0);  a1 = dot2(qreg[4 * u + 1], kv.y, a1);
      a0 = dot2(qreg[4 * u + 2], kv.z, a0);  a1 = dot2(qreg[4 * u + 3], kv.w, a1);
      a0 = dot2(qreg[4 * u + 0], tv0.x, a0); a1 = dot2(qreg[4 * u + 1], tv0.y, a1);
      a0 = dot2(qreg[4 * u + 2], tv1.x, a0); a1 = dot2(qreg[4 * u + 3], tv1.y, a1);
      a0 = dot2(qreg[4 * u + 0], dv0.x, a0); a1 = dot2(qreg[4 * u + 1], dv0.y, a1);
      a0 = dot2(qreg[4 * u + 2], dv1.x, a0); a1 = dot2(qreg[4 * u + 3], dv1.y, a1);
    }
    if (k <= q) sv[p] = (a0 + a1) * 0.125f;
    mx = fmaxf(mx, sv[p]);
  }
#pragma unroll
  for (int o = 32; o; o >>= 1) mx = fmaxf(mx, __shfl_xor(mx, o));
  float sum = 0.f;
  float ev[4];
#pragma unroll
  for (int p = 0; p < 4; ++p) {
    ev[p] = __expf(sv[p] - mx);
    sum += ev[p];
  }
#pragma unroll
  for (int o = 32; o; o >>= 1) sum += __shfl_xor(sum, o);
  float rs = 1.f / sum;
#pragma unroll
  for (int p = 0; p < 4; ++p) {
    if (p >= np) continue;
    int k = p * 64 + lane;
    if (k < Lc) sArow[wave][k] = ev[p] * rs;
  }
  // ---- output phase (same wave; LDS RAW handled by lgkmcnt) ----
  const float* Ar = sArow[wave];
  const ushort* tVh = (const ushort*)tVs;
  const ushort* dVh = (const ushort*)dVs;
  const ushort* Vb = V16 + rl(b * Lc * Hc + h * HSc) + lane;
  float acc0 = 0.f, acc1 = 0.f, acc2 = 0.f, acc3 = 0.f;
  int k0 = 0;
  for (; k0 + 7 <= q; k0 += 8) {
    float a_[8]; int ti_[8], di_[8];
#pragma unroll
    for (int u = 0; u < 8; ++u) { a_[u] = Ar[k0 + u]; ti_[u] = tmr[k0 + u]; di_[u] = dmr[k0 + u]; }
    float v_[8], tf_[8], df_[8];
#pragma unroll
    for (int u = 0; u < 8; ++u) {
      v_[u] = h2f(Vb[(k0 + u) * Hc]);
      tf_[u] = h2f(tVh[ti_[u] * 68 + lane]);
      df_[u] = h2f(dVh[di_[u] * 68 + lane]);
    }
    acc0 = fmaf(a_[0], v_[0] + tf_[0] + df_[0], acc0);
    acc1 = fmaf(a_[1], v_[1] + tf_[1] + df_[1], acc1);
    acc2 = fmaf(a_[2], v_[2] + tf_[2] + df_[2], acc2);
    acc3 = fmaf(a_[3], v_[3] + tf_[3] + df_[3], acc3);
    acc0 = fmaf(a_[4], v_[4] + tf_[4] + df_[4], acc0);
    acc1 = fmaf(a_[5], v_[5] + tf_[5] + df_[5], acc1);
    acc2 = fmaf(a_[6], v_[6] + tf_[6] + df_[6], acc2);
    acc3 = fmaf(a_[7], v_[7] + tf_[7] + df_[7], acc3);
  }
  for (; k0 <= q; ++k0) {
    float av = Ar[k0];
    int ti = tmr[k0], di = dmr[k0];
    float vv = h2f(Vb[k0 * Hc]);
    float tf = h2f(tVh[ti * 68 + lane]);
    float df = h2f(dVh[di * 68 + lane]);
    acc0 = fmaf(av, vv + tf + df, acc0);
  }
  seqs[oi] = Qn[oi] + (acc0 + acc1) + (acc2 + acc3);
}

extern "C" void kernel_launch(void* const* d_in, const int* in_sizes, int n_in,
                              void* d_out, int out_size, void* d_ws, size_t ws_size,
                              hipStream_t stream) {
  const int* logs = (const int*)d_in[0];
  const int* tm   = (const int*)d_in[1];
  const int* dm   = (const int*)d_in[2];
  const float* item = (const float*)d_in[3];
  const float* pK = (const float*)d_in[4];
  const float* pV = (const float*)d_in[5];
  const float* tK = (const float*)d_in[6];
  const float* tV = (const float*)d_in[7];
  const float* dK = (const float*)d_in[8];
  const float* dV = (const float*)d_in[9];
  const float* ln1_g = (const float*)d_in[10];
  const float* ln1_b = (const float*)d_in[11];
  const float* Wq = (const float*)d_in[12];
  const float* bq = (const float*)d_in[13];
  const float* Wk = (const float*)d_in[14];
  const float* bk = (const float*)d_in[15];
  const float* Wv = (const float*)d_in[16];
  const float* bv = (const float*)d_in[17];
  const float* ln2_g = (const float*)d_in[18];
  const float* ln2_b = (const float*)d_in[19];
  const float* W1 = (const float*)d_in[20];
  const float* b1 = (const float*)d_in[21];
  const float* W2 = (const float*)d_in[22];
  const float* b2 = (const float*)d_in[23];
  const float* lnf_g = (const float*)d_in[24];
  const float* lnf_b = (const float*)d_in[25];

  const int NROW = Mtot * Hc;          // 204800 floats
  float* ws = (float*)d_ws;
  float* sSeqs = ws + 0 * NROW;
  float* sQn   = ws + 1 * NROW;
  float* sX    = ws + 2 * NROW;
  float* sH    = ws + 3 * NROW;
  ushort* Q16  = (ushort*)(ws + 4 * NROW);
  ushort* K16  = Q16 + NROW;
  ushort* V16  = K16 + NROW;

  embed_k<<<NROW / 256, 256, 0, stream>>>(logs, item, sSeqs);

  dim3 gQKV(Mtot / 16, 12);
  dim3 gFFN(Mtot / 16, 4);
  dim3 ga(NHc, Bc, 16);                // 256 blocks x 1024 threads
  const int HH = Hc * Hc;
  for (int i = 0; i < NBc; ++i) {
    ln_k<<<Mtot, Hc, 0, stream>>>(sSeqs, ln1_g + i * Hc, ln1_b + i * Hc, sQn);
    mm_k<0><<<gQKV, 256, 0, stream>>>(sQn, sSeqs,
                                      Wq + i * HH, Wk + i * HH, Wv + i * HH,
                                      bq + i * Hc, bk + i * Hc, bv + i * Hc,
                                      pK, pV, nullptr, nullptr, Q16, K16, V16);
    attn_k<<<ga, 1024, 0, stream>>>((const uint*)Q16, (const uint*)K16, V16,
                                    tK, dK, tV, dV, tm, dm, logs, sQn, sSeqs);
    ln_k<<<Mtot, Hc, 0, stream>>>(sSeqs, ln2_g + i * Hc, ln2_b + i * Hc, sX);
    mm_k<1><<<gFFN, 256, 0, stream>>>(sX, nullptr, W1 + i * HH, nullptr, nullptr,
                                      b1 + i * Hc, nullptr, nullptr,
                                      nullptr, nullptr, nullptr, nullptr,
                                      sH, nullptr, nullptr);
    mm_k<2><<<gFFN, 256, 0, stream>>>(sH, nullptr, W2 + i * HH, nullptr, nullptr,
                                      b2 + i * Hc, nullptr, nullptr,
                                      nullptr, nullptr, sX, logs,
                                      sSeqs, nullptr, nullptr);
  }
  ln_k<<<Mtot, Hc, 0, stream>>>(sSeqs, lnf_g, lnf_b, (float*)d_out);
}

// Round 8
// 117.157 us; speedup vs baseline: 4.3700x; 1.0121x over previous
//
#include <hip/hip_runtime.h>
#include <math.h>

typedef __fp16 h2 __attribute__((ext_vector_type(2)));
typedef __fp16 f16x8 __attribute__((ext_vector_type(8)));
typedef float f32x4 __attribute__((ext_vector_type(4)));

#define Bc 4
#define Lc 200
#define Hc 256
#define NHc 4
#define HSc 64
#define NBc 2
#define Mtot (Bc*Lc)   // 800
#define TROW 34        // LDS table row stride in u32 (68 halfs = 136B)
#define LDH 264        // mm LDS row stride in halves (528B)

static __device__ __forceinline__ float neg_fill() { return -4294967295.0f; }
static __device__ __forceinline__ int rl(int x) { return __builtin_amdgcn_readfirstlane(x); }

static __device__ __forceinline__ uint pkh2(float a, float b) {
  h2 r = __builtin_amdgcn_cvt_pkrtz(a, b);
  return __builtin_bit_cast(uint, r);
}
#if __has_builtin(__builtin_amdgcn_fdot2)
static __device__ __forceinline__ float dot2(uint a, uint b, float c) {
  return __builtin_amdgcn_fdot2(__builtin_bit_cast(h2, a), __builtin_bit_cast(h2, b), c, false);
}
#else
static __device__ __forceinline__ float dot2(uint a, uint b, float c) {
  h2 x = __builtin_bit_cast(h2, a), y = __builtin_bit_cast(h2, b);
  return c + (float)x.x * (float)y.x + (float)x.y * (float)y.y;
}
#endif
static __device__ __forceinline__ float h2f(ushort u) {
  return (float)__builtin_bit_cast(_Float16, u);
}

// ---------------- embedding + keep mask ----------------
__global__ void embed_k(const int* __restrict__ logs, const float* __restrict__ emb,
                        float* __restrict__ seqs) {
  int idx = blockIdx.x * 256 + threadIdx.x;
  int hcol = idx & (Hc - 1);
  int bl = idx >> 8;
  int tok = logs[bl];
  seqs[idx] = (tok == 0) ? 0.f : emb[tok * Hc + hcol];
}

// ---------------- layernorm over H=256, one block per row (final only) -------
__global__ void ln_k(const float* __restrict__ x, const float* __restrict__ g,
                     const float* __restrict__ bt, float* __restrict__ y) {
  int row = blockIdx.x;
  int t = threadIdx.x;
  float v = x[row * Hc + t];
  float a = v, sq = v * v;
  for (int o = 32; o; o >>= 1) { a += __shfl_down(a, o); sq += __shfl_down(sq, o); }
  __shared__ float s1[4], s2[4];
  __shared__ float mS, rS;
  int wave = t >> 6, lane = t & 63;
  if (lane == 0) { s1[wave] = a; s2[wave] = sq; }
  __syncthreads();
  if (t == 0) {
    float sum = s1[0] + s1[1] + s1[2] + s1[3];
    float ssq = s2[0] + s2[1] + s2[2] + s2[3];
    float m = sum * (1.f / Hc);
    float var = ssq * (1.f / Hc) - m * m;
    mS = m;
    rS = 1.f / sqrtf(var + 1e-8f);
  }
  __syncthreads();
  y[row * Hc + t] = (v - mS) * rS * g[t] + bt[t];
}

// ---------------- fused LN1 + QKV projections ----------------
// grid (50, 12): y>>2 = region (0=Q,1=K,2=V), y&3 -> n-chunk of 64.
// Region 0 computes LN1 of the 16-row tile in-block (A = LN(seqs)); y==0 also
// writes Qn (f32) for the attention residual. Regions 1,2 use raw seqs.
__global__ __launch_bounds__(256)
void mmqkv_k(const float* __restrict__ seqs,
             const float* __restrict__ g, const float* __restrict__ bt,
             const float* __restrict__ Wq, const float* __restrict__ Wk,
             const float* __restrict__ Wv,
             const float* __restrict__ bq, const float* __restrict__ bk,
             const float* __restrict__ bv,
             const float* __restrict__ pK, const float* __restrict__ pV,
             float* __restrict__ Qn,
             ushort* __restrict__ Q16, ushort* __restrict__ K16,
             ushort* __restrict__ V16) {
  __shared__ __fp16 Al[16][LDH];
  __shared__ __fp16 Wl[64][LDH];
  int m0 = blockIdx.x * 16;
  int y = blockIdx.y;
  int region = y >> 2, nloc = (y & 3) * 64;
  const float* Wsrc = (region == 0) ? Wq : (region == 1 ? Wk : Wv);
  const float* bias = (region == 0) ? bq : (region == 1 ? bk : bv);
  int t = threadIdx.x;
  if (region == 0) {
    // LN1 of rows m0..m0+15: 16 threads per row, 16 cols each
    int r = t >> 4, c0 = (t & 15) * 16;
    const float* xr = &seqs[(m0 + r) * Hc + c0];
    float4 v0 = *(const float4*)&xr[0];
    float4 v1 = *(const float4*)&xr[4];
    float4 v2 = *(const float4*)&xr[8];
    float4 v3 = *(const float4*)&xr[12];
    float s = v0.x + v0.y + v0.z + v0.w + v1.x + v1.y + v1.z + v1.w
            + v2.x + v2.y + v2.z + v2.w + v3.x + v3.y + v3.z + v3.w;
    float q = v0.x*v0.x + v0.y*v0.y + v0.z*v0.z + v0.w*v0.w
            + v1.x*v1.x + v1.y*v1.y + v1.z*v1.z + v1.w*v1.w
            + v2.x*v2.x + v2.y*v2.y + v2.z*v2.z + v2.w*v2.w
            + v3.x*v3.x + v3.y*v3.y + v3.z*v3.z + v3.w*v3.w;
#pragma unroll
    for (int o = 1; o < 16; o <<= 1) { s += __shfl_xor(s, o); q += __shfl_xor(q, o); }
    float mean = s * (1.f / Hc);
    float var = q * (1.f / Hc) - mean * mean;
    float rstd = 1.f / sqrtf(var + 1e-8f);
    float nv[16];
    const float* vv = &v0.x;   // contiguous 16 floats (v0..v3 are consecutive on stack)
    float tmp[16] = {v0.x,v0.y,v0.z,v0.w,v1.x,v1.y,v1.z,v1.w,
                     v2.x,v2.y,v2.z,v2.w,v3.x,v3.y,v3.z,v3.w};
#pragma unroll
    for (int j = 0; j < 16; ++j)
      nv[j] = (tmp[j] - mean) * rstd * g[c0 + j] + bt[c0 + j];
#pragma unroll
    for (int j = 0; j < 16; j += 2)
      *(h2*)&Al[r][c0 + j] = __builtin_amdgcn_cvt_pkrtz(nv[j], nv[j + 1]);
    if (y == 0) {
#pragma unroll
      for (int j = 0; j < 16; j += 4)
        *(float4*)&Qn[(m0 + r) * Hc + c0 + j] = make_float4(nv[j], nv[j+1], nv[j+2], nv[j+3]);
    }
    (void)vv;
  } else {
    for (int i = t; i < 16 * 64; i += 256) {
      int r = i >> 6, c = (i & 63) * 4;
      float4 v = *(const float4*)&seqs[(m0 + r) * Hc + c];
      *(h2*)&Al[r][c] = __builtin_amdgcn_cvt_pkrtz(v.x, v.y);
      *(h2*)&Al[r][c + 2] = __builtin_amdgcn_cvt_pkrtz(v.z, v.w);
    }
  }
  for (int i = t; i < 64 * 64; i += 256) {
    int r = i >> 6, c = (i & 63) * 4;
    float4 v = *(const float4*)&Wsrc[(nloc + r) * Hc + c];
    *(h2*)&Wl[r][c] = __builtin_amdgcn_cvt_pkrtz(v.x, v.y);
    *(h2*)&Wl[r][c + 2] = __builtin_amdgcn_cvt_pkrtz(v.z, v.w);
  }
  __syncthreads();
  int wave = t >> 6, lane = t & 63;
  int row = lane & 15, kg = lane >> 4;
  int bn = wave * 16 + row;
  f32x4 acc = {0.f, 0.f, 0.f, 0.f};
#pragma unroll
  for (int k0 = 0; k0 < Hc; k0 += 32) {
    int kk = k0 + kg * 8;
    f16x8 a = *(const f16x8*)&Al[row][kk];
    f16x8 bb = *(const f16x8*)&Wl[bn][kk];
    acc = __builtin_amdgcn_mfma_f32_16x16x32_f16(a, bb, acc, 0, 0, 0);
  }
  int coln = nloc + wave * 16 + row;
  ushort* op = (region == 0) ? Q16 : (region == 1 ? K16 : V16);
  const float* pT = (region == 1) ? pK : pV;
#pragma unroll
  for (int r = 0; r < 4; ++r) {
    int m = m0 + kg * 4 + r;
    float v = acc[r] + bias[coln];
    if (region) v += pT[(m % Lc) * Hc + coln];
    op[m * Hc + coln] = __builtin_bit_cast(ushort, (_Float16)v);
  }
}

// ---------------- fused attention: scores + softmax + output + residual ------
// grid (NHc, Bc, 16) = 256 blocks; block 1024 (16 waves), one q-row per wave.
__global__ __launch_bounds__(1024, 4)
void attn_k(const uint* __restrict__ Q16, const uint* __restrict__ K16,
            const ushort* __restrict__ V16,
            const float* __restrict__ tK, const float* __restrict__ dK,
            const float* __restrict__ tV, const float* __restrict__ dV,
            const int* __restrict__ tm, const int* __restrict__ dm,
            const int* __restrict__ logs,
            const float* __restrict__ Qn, float* __restrict__ seqs) {
  int h = blockIdx.x, b = blockIdx.y, bz = blockIdx.z;
  __shared__ uint tKs[257 * TROW];
  __shared__ uint dKs[257 * TROW];
  __shared__ uint tVs[257 * TROW];
  __shared__ uint dVs[257 * TROW];
  __shared__ float sArow[16][204];
  int t = threadIdx.x;
  for (int i = t; i < 257 * 16; i += 1024) {
    int r = i >> 4, c4 = (i & 15) * 4;
    float4 a = *(const float4*)&tK[r * Hc + h * HSc + c4];
    float4 c = *(const float4*)&dK[r * Hc + h * HSc + c4];
    float4 e = *(const float4*)&tV[r * Hc + h * HSc + c4];
    float4 f = *(const float4*)&dV[r * Hc + h * HSc + c4];
    *(uint2*)&tKs[r * TROW + (c4 >> 1)] = make_uint2(pkh2(a.x, a.y), pkh2(a.z, a.w));
    *(uint2*)&dKs[r * TROW + (c4 >> 1)] = make_uint2(pkh2(c.x, c.y), pkh2(c.z, c.w));
    *(uint2*)&tVs[r * TROW + (c4 >> 1)] = make_uint2(pkh2(e.x, e.y), pkh2(e.z, e.w));
    *(uint2*)&dVs[r * TROW + (c4 >> 1)] = make_uint2(pkh2(f.x, f.y), pkh2(f.z, f.w));
  }
  __syncthreads();
  int wave = t >> 6, lane = t & 63;
  int z = h * 4 + b;
  int q = wave * 16 + bz;
  if (q >= Lc) return;
  int m = b * Lc + q;
  int oi = m * Hc + h * HSc + lane;
  if (logs[m] == 0) { seqs[oi] = Qn[oi]; return; }
  const int* tmr = tm + rl(m * Lc);
  const int* dmr = dm + rl(m * Lc);
  const uint* Qr = Q16 + rl(m * (Hc / 2) + h * (HSc / 2));
  uint qreg[32];
#pragma unroll
  for (int u = 0; u < 32; ++u) qreg[u] = Qr[u];
  int np = (q >> 6) + 1;
  float sv[4];
  float mx = neg_fill();
#pragma unroll
  for (int p = 0; p < 4; ++p) {
    sv[p] = neg_fill();
    if (p >= np) continue;
    int k = p * 64 + lane;
    int kc = (k <= q) ? k : q;
    int ti = tmr[kc], di = dmr[kc];
    const uint2* tr = (const uint2*)&tKs[ti * TROW];
    const uint2* dr = (const uint2*)&dKs[di * TROW];
    const uint4* Kr = (const uint4*)&K16[(b * Lc + kc) * (Hc / 2) + h * (HSc / 2)];
    float a0 = 0.f, a1 = 0.f;
#pragma unroll
    for (int u = 0; u < 8; ++u) {
      uint4 kv = Kr[u];
      uint2 tv0 = tr[2 * u], tv1 = tr[2 * u + 1];
      uint2 dv0 = dr[2 * u], dv1 = dr[2 * u + 1];
      a0 = dot2(qreg[4 * u + 0], kv.x, a0);  a1 = dot2(qreg[4 * u + 1], kv.y, a1);
      a0 = dot2(qreg[4 * u + 2], kv.z, a0);  a1 = dot2(qreg[4 * u + 3], kv.w, a1);
      a0 = dot2(qreg[4 * u + 0], tv0.x, a0); a1 = dot2(qreg[4 * u + 1], tv0.y, a1);
      a0 = dot2(qreg[4 * u + 2], tv1.x, a0); a1 = dot2(qreg[4 * u + 3], tv1.y, a1);
      a0 = dot2(qreg[4 * u + 0], dv0.x, a0); a1 = dot2(qreg[4 * u + 1], dv0.y, a1);
      a0 = dot2(qreg[4 * u + 2], dv1.x, a0); a1 = dot2(qreg[4 * u + 3], dv1.y, a1);
    }
    if (k <= q) sv[p] = (a0 + a1) * 0.125f;
    mx = fmaxf(mx, sv[p]);
  }
#pragma unroll
  for (int o = 32; o; o >>= 1) mx = fmaxf(mx, __shfl_xor(mx, o));
  float sum = 0.f;
  float ev[4];
#pragma unroll
  for (int p = 0; p < 4; ++p) {
    ev[p] = __expf(sv[p] - mx);
    sum += ev[p];
  }
#pragma unroll
  for (int o = 32; o; o >>= 1) sum += __shfl_xor(sum, o);
  float rs = 1.f / sum;
#pragma unroll
  for (int p = 0; p < 4; ++p) {
    if (p >= np) continue;
    int k = p * 64 + lane;
    if (k < Lc) sArow[wave][k] = ev[p] * rs;
  }
  const float* Ar = sArow[wave];
  const ushort* tVh = (const ushort*)tVs;
  const ushort* dVh = (const ushort*)dVs;
  const ushort* Vb = V16 + rl(b * Lc * Hc + h * HSc) + lane;
  float acc0 = 0.f, acc1 = 0.f, acc2 = 0.f, acc3 = 0.f;
  int k0 = 0;
  for (; k0 + 7 <= q; k0 += 8) {
    float a_[8]; int ti_[8], di_[8];
#pragma unroll
    for (int u = 0; u < 8; ++u) { a_[u] = Ar[k0 + u]; ti_[u] = tmr[k0 + u]; di_[u] = dmr[k0 + u]; }
    float v_[8], tf_[8], df_[8];
#pragma unroll
    for (int u = 0; u < 8; ++u) {
      v_[u] = h2f(Vb[(k0 + u) * Hc]);
      tf_[u] = h2f(tVh[ti_[u] * 68 + lane]);
      df_[u] = h2f(dVh[di_[u] * 68 + lane]);
    }
    acc0 = fmaf(a_[0], v_[0] + tf_[0] + df_[0], acc0);
    acc1 = fmaf(a_[1], v_[1] + tf_[1] + df_[1], acc1);
    acc2 = fmaf(a_[2], v_[2] + tf_[2] + df_[2], acc2);
    acc3 = fmaf(a_[3], v_[3] + tf_[3] + df_[3], acc3);
    acc0 = fmaf(a_[4], v_[4] + tf_[4] + df_[4], acc0);
    acc1 = fmaf(a_[5], v_[5] + tf_[5] + df_[5], acc1);
    acc2 = fmaf(a_[6], v_[6] + tf_[6] + df_[6], acc2);
    acc3 = fmaf(a_[7], v_[7] + tf_[7] + df_[7], acc3);
  }
  for (; k0 <= q; ++k0) {
    float av = Ar[k0];
    int ti = tmr[k0], di = dmr[k0];
    float vv = h2f(Vb[k0 * Hc]);
    float tf = h2f(tVh[ti * 68 + lane]);
    float df = h2f(dVh[di * 68 + lane]);
    acc0 = fmaf(av, vv + tf + df, acc0);
  }
  seqs[oi] = Qn[oi] + (acc0 + acc1) + (acc2 + acc3);
}

// ---------------- fused LN2 + FFN1(relu) + FFN2 + residual + keep ----------
// grid (50); block 512 (8 waves). W staged in 128-row chunks.
__global__ __launch_bounds__(512)
void ffn_k(float* __restrict__ seqs,
           const float* __restrict__ g, const float* __restrict__ bt,
           const float* __restrict__ W1, const float* __restrict__ b1,
           const float* __restrict__ W2, const float* __restrict__ b2,
           const int* __restrict__ logs) {
  __shared__ __fp16 Xl[16][LDH];
  __shared__ __fp16 Hl[16][LDH];
  __shared__ __fp16 Wl[128][LDH];
  int m0 = blockIdx.x * 16;
  int t = threadIdx.x;
  // ---- LN2: 32 threads per row, 8 cols each ----
  {
    int r = t >> 5, c0 = (t & 31) * 8;
    const float* xr = &seqs[(m0 + r) * Hc + c0];
    float4 v0 = *(const float4*)&xr[0];
    float4 v1 = *(const float4*)&xr[4];
    float s = v0.x + v0.y + v0.z + v0.w + v1.x + v1.y + v1.z + v1.w;
    float q = v0.x*v0.x + v0.y*v0.y + v0.z*v0.z + v0.w*v0.w
            + v1.x*v1.x + v1.y*v1.y + v1.z*v1.z + v1.w*v1.w;
#pragma unroll
    for (int o = 1; o < 32; o <<= 1) { s += __shfl_xor(s, o); q += __shfl_xor(q, o); }
    float mean = s * (1.f / Hc);
    float var = q * (1.f / Hc) - mean * mean;
    float rstd = 1.f / sqrtf(var + 1e-8f);
    float tmp[8] = {v0.x,v0.y,v0.z,v0.w,v1.x,v1.y,v1.z,v1.w};
    float nv[8];
#pragma unroll
    for (int j = 0; j < 8; ++j)
      nv[j] = (tmp[j] - mean) * rstd * g[c0 + j] + bt[c0 + j];
#pragma unroll
    for (int j = 0; j < 8; j += 2)
      *(h2*)&Xl[r][c0 + j] = __builtin_amdgcn_cvt_pkrtz(nv[j], nv[j + 1]);
  }
  int wave = t >> 6, lane = t & 63;
  int row = lane & 15, kg = lane >> 4;
  // ---- FFN1: H = relu(X @ W1^T + b1) ----
#pragma unroll
  for (int ch = 0; ch < 2; ++ch) {
    __syncthreads();
    for (int i = t; i < 128 * 64; i += 512) {
      int r = i >> 6, c = (i & 63) * 4;
      float4 v = *(const float4*)&W1[(ch * 128 + r) * Hc + c];
      *(h2*)&Wl[r][c] = __builtin_amdgcn_cvt_pkrtz(v.x, v.y);
      *(h2*)&Wl[r][c + 2] = __builtin_amdgcn_cvt_pkrtz(v.z, v.w);
    }
    __syncthreads();
    int bn = wave * 16 + row;
    f32x4 acc = {0.f, 0.f, 0.f, 0.f};
#pragma unroll
    for (int k0 = 0; k0 < Hc; k0 += 32) {
      int kk = k0 + kg * 8;
      f16x8 a = *(const f16x8*)&Xl[row][kk];
      f16x8 bb = *(const f16x8*)&Wl[bn][kk];
      acc = __builtin_amdgcn_mfma_f32_16x16x32_f16(a, bb, acc, 0, 0, 0);
    }
    int coln = ch * 128 + wave * 16 + row;
    float bv = b1[coln];
#pragma unroll
    for (int r = 0; r < 4; ++r) {
      float v = fmaxf(acc[r] + bv, 0.f);
      Hl[kg * 4 + r][coln] = (_Float16)v;
    }
  }
  // ---- FFN2: seqs = (H @ W2^T + b2 + X) * keep ----
#pragma unroll
  for (int ch = 0; ch < 2; ++ch) {
    __syncthreads();
    for (int i = t; i < 128 * 64; i += 512) {
      int r = i >> 6, c = (i & 63) * 4;
      float4 v = *(const float4*)&W2[(ch * 128 + r) * Hc + c];
      *(h2*)&Wl[r][c] = __builtin_amdgcn_cvt_pkrtz(v.x, v.y);
      *(h2*)&Wl[r][c + 2] = __builtin_amdgcn_cvt_pkrtz(v.z, v.w);
    }
    __syncthreads();
    int bn = wave * 16 + row;
    f32x4 acc = {0.f, 0.f, 0.f, 0.f};
#pragma unroll
    for (int k0 = 0; k0 < Hc; k0 += 32) {
      int kk = k0 + kg * 8;
      f16x8 a = *(const f16x8*)&Hl[row][kk];
      f16x8 bb = *(const f16x8*)&Wl[bn][kk];
      acc = __builtin_amdgcn_mfma_f32_16x16x32_f16(a, bb, acc, 0, 0, 0);
    }
    int coln = ch * 128 + wave * 16 + row;
    float bv = b2[coln];
#pragma unroll
    for (int r = 0; r < 4; ++r) {
      int mrow = kg * 4 + r;
      int m = m0 + mrow;
      float keep = (logs[m] != 0) ? 1.f : 0.f;
      float xv = h2f(__builtin_bit_cast(ushort, Xl[mrow][coln]));
      seqs[m * Hc + coln] = (acc[r] + bv + xv) * keep;
    }
  }
}

extern "C" void kernel_launch(void* const* d_in, const int* in_sizes, int n_in,
                              void* d_out, int out_size, void* d_ws, size_t ws_size,
                              hipStream_t stream) {
  const int* logs = (const int*)d_in[0];
  const int* tm   = (const int*)d_in[1];
  const int* dm   = (const int*)d_in[2];
  const float* item = (const float*)d_in[3];
  const float* pK = (const float*)d_in[4];
  const float* pV = (const float*)d_in[5];
  const float* tK = (const float*)d_in[6];
  const float* tV = (const float*)d_in[7];
  const float* dK = (const float*)d_in[8];
  const float* dV = (const float*)d_in[9];
  const float* ln1_g = (const float*)d_in[10];
  const float* ln1_b = (const float*)d_in[11];
  const float* Wq = (const float*)d_in[12];
  const float* bq = (const float*)d_in[13];
  const float* Wk = (const float*)d_in[14];
  const float* bk = (const float*)d_in[15];
  const float* Wv = (const float*)d_in[16];
  const float* bv = (const float*)d_in[17];
  const float* ln2_g = (const float*)d_in[18];
  const float* ln2_b = (const float*)d_in[19];
  const float* W1 = (const float*)d_in[20];
  const float* b1 = (const float*)d_in[21];
  const float* W2 = (const float*)d_in[22];
  const float* b2 = (const float*)d_in[23];
  const float* lnf_g = (const float*)d_in[24];
  const float* lnf_b = (const float*)d_in[25];

  const int NROW = Mtot * Hc;          // 204800 floats
  float* ws = (float*)d_ws;
  float* sSeqs = ws + 0 * NROW;
  float* sQn   = ws + 1 * NROW;
  ushort* Q16  = (ushort*)(ws + 2 * NROW);
  ushort* K16  = Q16 + NROW;
  ushort* V16  = K16 + NROW;

  embed_k<<<NROW / 256, 256, 0, stream>>>(logs, item, sSeqs);

  dim3 gQKV(Mtot / 16, 12);
  dim3 ga(NHc, Bc, 16);
  const int HH = Hc * Hc;
  for (int i = 0; i < NBc; ++i) {
    mmqkv_k<<<gQKV, 256, 0, stream>>>(sSeqs, ln1_g + i * Hc, ln1_b + i * Hc,
                                      Wq + i * HH, Wk + i * HH, Wv + i * HH,
                                      bq + i * Hc, bk + i * Hc, bv + i * Hc,
                                      pK, pV, sQn, Q16, K16, V16);
    attn_k<<<ga, 1024, 0, stream>>>((const uint*)Q16, (const uint*)K16, V16,
                                    tK, dK, tV, dV, tm, dm, logs, sQn, sSeqs);
    ffn_k<<<Mtot / 16, 512, 0, stream>>>(sSeqs, ln2_g + i * Hc, ln2_b + i * Hc,
                                         W1 + i * HH, b1 + i * Hc,
                                         W2 + i * HH, b2 + i * Hc, logs);
  }
  ln_k<<<Mtot, Hc, 0, stream>>>(sSeqs, lnf_g, lnf_b, (float*)d_out);
}

// Round 9
// 87.108 us; speedup vs baseline: 5.8775x; 1.3450x over previous
//
#include <hip/hip_runtime.h>
#include <math.h>

typedef __fp16 h2 __attribute__((ext_vector_type(2)));
typedef __fp16 f16x8 __attribute__((ext_vector_type(8)));
typedef float f32x4 __attribute__((ext_vector_type(4)));

#define Bc 4
#define Lc 200
#define Hc 256
#define NHc 4
#define HSc 64
#define NBc 2
#define Mtot (Bc*Lc)   // 800
#define TROW 34        // LDS table row stride in u32 (68 halfs = 136B)
#define LDH 264        // mm LDS row stride in halves (528B)
#define WN (2*Hc*Hc)   // 131072 halves per weight array (both layers)
#define TN (257*Hc)    // 65792 halves per table

static __device__ __forceinline__ float neg_fill() { return -4294967295.0f; }
static __device__ __forceinline__ int rl(int x) { return __builtin_amdgcn_readfirstlane(x); }

static __device__ __forceinline__ uint pkh2(float a, float b) {
  h2 r = __builtin_amdgcn_cvt_pkrtz(a, b);
  return __builtin_bit_cast(uint, r);
}
static __device__ __forceinline__ h2 u2h(uint u) { return __builtin_bit_cast(h2, u); }
#if __has_builtin(__builtin_amdgcn_fdot2)
static __device__ __forceinline__ float dot2(uint a, uint b, float c) {
  return __builtin_amdgcn_fdot2(u2h(a), u2h(b), c, false);
}
#else
static __device__ __forceinline__ float dot2(uint a, uint b, float c) {
  h2 x = u2h(a), y = u2h(b);
  return c + (float)x.x * (float)y.x + (float)x.y * (float)y.y;
}
#endif
static __device__ __forceinline__ float h2f(ushort u) {
  return (float)__builtin_bit_cast(_Float16, u);
}

// ---------------- one-shot f32 -> f16 conversion of weights & tables --------
// out: [Wq|Wk|Wv|W1|W2] (WN each, both layers) then [tK|tV|dK|dV] (TN each)
__global__ void cvtw_k(const float* __restrict__ Wq, const float* __restrict__ Wk,
                       const float* __restrict__ Wv, const float* __restrict__ W1,
                       const float* __restrict__ W2,
                       const float* __restrict__ tK, const float* __restrict__ tV,
                       const float* __restrict__ dK, const float* __restrict__ dV,
                       ushort* __restrict__ out) {
  int y = blockIdx.y;
  const float* src;
  int n, off;
  if (y < 5) {
    n = WN; off = y * WN;
    src = (y == 0) ? Wq : (y == 1) ? Wk : (y == 2) ? Wv : (y == 3) ? W1 : W2;
  } else {
    n = TN; off = 5 * WN + (y - 5) * TN;
    src = (y == 5) ? tK : (y == 6) ? tV : (y == 7) ? dK : dV;
  }
  int idx = (blockIdx.x * 256 + threadIdx.x) * 8;
  if (idx >= n) return;
  float4 a = *(const float4*)&src[idx];
  float4 b = *(const float4*)&src[idx + 4];
  uint4 o;
  o.x = pkh2(a.x, a.y); o.y = pkh2(a.z, a.w);
  o.z = pkh2(b.x, b.y); o.w = pkh2(b.z, b.w);
  *(uint4*)&out[off + idx] = o;
}

// ---------------- embedding + keep mask ----------------
__global__ void embed_k(const int* __restrict__ logs, const float* __restrict__ emb,
                        float* __restrict__ seqs) {
  int idx = blockIdx.x * 256 + threadIdx.x;
  int hcol = idx & (Hc - 1);
  int bl = idx >> 8;
  int tok = logs[bl];
  seqs[idx] = (tok == 0) ? 0.f : emb[tok * Hc + hcol];
}

// ---------------- layernorm (final) ----------------
__global__ void ln_k(const float* __restrict__ x, const float* __restrict__ g,
                     const float* __restrict__ bt, float* __restrict__ y) {
  int row = blockIdx.x;
  int t = threadIdx.x;
  float v = x[row * Hc + t];
  float a = v, sq = v * v;
  for (int o = 32; o; o >>= 1) { a += __shfl_down(a, o); sq += __shfl_down(sq, o); }
  __shared__ float s1[4], s2[4];
  __shared__ float mS, rS;
  int wave = t >> 6, lane = t & 63;
  if (lane == 0) { s1[wave] = a; s2[wave] = sq; }
  __syncthreads();
  if (t == 0) {
    float sum = s1[0] + s1[1] + s1[2] + s1[3];
    float ssq = s2[0] + s2[1] + s2[2] + s2[3];
    float m = sum * (1.f / Hc);
    float var = ssq * (1.f / Hc) - m * m;
    mS = m;
    rS = 1.f / sqrtf(var + 1e-8f);
  }
  __syncthreads();
  y[row * Hc + t] = (v - mS) * rS * g[t] + bt[t];
}

// ---------------- fused LN1 + QKV projections (f16 weights) ----------------
__global__ __launch_bounds__(256)
void mmqkv_k(const float* __restrict__ seqs,
             const float* __restrict__ g, const float* __restrict__ bt,
             const ushort* __restrict__ Wq16, const ushort* __restrict__ Wk16,
             const ushort* __restrict__ Wv16,
             const float* __restrict__ bq, const float* __restrict__ bk,
             const float* __restrict__ bv,
             const float* __restrict__ pK, const float* __restrict__ pV,
             float* __restrict__ Qn,
             ushort* __restrict__ Q16, ushort* __restrict__ K16,
             ushort* __restrict__ V16) {
  __shared__ __fp16 Al[16][LDH];
  __shared__ __fp16 Wl[64][LDH];
  int m0 = blockIdx.x * 16;
  int y = blockIdx.y;
  int region = y >> 2, nloc = (y & 3) * 64;
  const ushort* Wsrc = (region == 0) ? Wq16 : (region == 1 ? Wk16 : Wv16);
  const float* bias = (region == 0) ? bq : (region == 1 ? bk : bv);
  int t = threadIdx.x;
  if (region == 0) {
    int r = t >> 4, c0 = (t & 15) * 16;
    const float* xr = &seqs[(m0 + r) * Hc + c0];
    float4 v0 = *(const float4*)&xr[0];
    float4 v1 = *(const float4*)&xr[4];
    float4 v2 = *(const float4*)&xr[8];
    float4 v3 = *(const float4*)&xr[12];
    float s = v0.x + v0.y + v0.z + v0.w + v1.x + v1.y + v1.z + v1.w
            + v2.x + v2.y + v2.z + v2.w + v3.x + v3.y + v3.z + v3.w;
    float q = v0.x*v0.x + v0.y*v0.y + v0.z*v0.z + v0.w*v0.w
            + v1.x*v1.x + v1.y*v1.y + v1.z*v1.z + v1.w*v1.w
            + v2.x*v2.x + v2.y*v2.y + v2.z*v2.z + v2.w*v2.w
            + v3.x*v3.x + v3.y*v3.y + v3.z*v3.z + v3.w*v3.w;
#pragma unroll
    for (int o = 1; o < 16; o <<= 1) { s += __shfl_xor(s, o); q += __shfl_xor(q, o); }
    float mean = s * (1.f / Hc);
    float var = q * (1.f / Hc) - mean * mean;
    float rstd = 1.f / sqrtf(var + 1e-8f);
    float tmp[16] = {v0.x,v0.y,v0.z,v0.w,v1.x,v1.y,v1.z,v1.w,
                     v2.x,v2.y,v2.z,v2.w,v3.x,v3.y,v3.z,v3.w};
    float nv[16];
#pragma unroll
    for (int j = 0; j < 16; ++j)
      nv[j] = (tmp[j] - mean) * rstd * g[c0 + j] + bt[c0 + j];
#pragma unroll
    for (int j = 0; j < 16; j += 2)
      *(h2*)&Al[r][c0 + j] = __builtin_amdgcn_cvt_pkrtz(nv[j], nv[j + 1]);
    if (y == 0) {
#pragma unroll
      for (int j = 0; j < 16; j += 4)
        *(float4*)&Qn[(m0 + r) * Hc + c0 + j] = make_float4(nv[j], nv[j+1], nv[j+2], nv[j+3]);
    }
  } else {
    for (int i = t; i < 16 * 64; i += 256) {
      int r = i >> 6, c = (i & 63) * 4;
      float4 v = *(const float4*)&seqs[(m0 + r) * Hc + c];
      *(h2*)&Al[r][c] = __builtin_amdgcn_cvt_pkrtz(v.x, v.y);
      *(h2*)&Al[r][c + 2] = __builtin_amdgcn_cvt_pkrtz(v.z, v.w);
    }
  }
  // W staging: pure f16 copy, 8 uint4 per thread
  for (int i = t; i < 2048; i += 256) {
    int r = i >> 5, c = (i & 31) * 8;
    uint4 v = *(const uint4*)&Wsrc[(nloc + r) * Hc + c];
    *(uint4*)&Wl[r][c] = v;
  }
  __syncthreads();
  int wave = t >> 6, lane = t & 63;
  int row = lane & 15, kg = lane >> 4;
  int bn = wave * 16 + row;
  f32x4 acc = {0.f, 0.f, 0.f, 0.f};
#pragma unroll
  for (int k0 = 0; k0 < Hc; k0 += 32) {
    int kk = k0 + kg * 8;
    f16x8 a = *(const f16x8*)&Al[row][kk];
    f16x8 bb = *(const f16x8*)&Wl[bn][kk];
    acc = __builtin_amdgcn_mfma_f32_16x16x32_f16(a, bb, acc, 0, 0, 0);
  }
  int coln = nloc + wave * 16 + row;
  ushort* op = (region == 0) ? Q16 : (region == 1 ? K16 : V16);
  const float* pT = (region == 1) ? pK : pV;
#pragma unroll
  for (int r = 0; r < 4; ++r) {
    int m = m0 + kg * 4 + r;
    float v = acc[r] + bias[coln];
    if (region) v += pT[(m % Lc) * Hc + coln];
    op[m * Hc + coln] = __builtin_bit_cast(ushort, (_Float16)v);
  }
}

// ---------------- fused attention (f16 tables; paired-k out phase) ----------
// grid (NHc, Bc, 16) = 256 blocks; block 1024 (16 waves), one q-row per wave.
__global__ __launch_bounds__(1024, 4)
void attn_k(const uint* __restrict__ Q16, const uint* __restrict__ K16,
            const ushort* __restrict__ V16,
            const ushort* __restrict__ tK16, const ushort* __restrict__ dK16,
            const ushort* __restrict__ tV16, const ushort* __restrict__ dV16,
            const int* __restrict__ tm, const int* __restrict__ dm,
            const int* __restrict__ logs,
            const float* __restrict__ Qn, float* __restrict__ seqs) {
  int h = blockIdx.x, b = blockIdx.y, bz = blockIdx.z;
  __shared__ uint tKs[257 * TROW];
  __shared__ uint dKs[257 * TROW];
  __shared__ uint tVs[257 * TROW];
  __shared__ uint dVs[257 * TROW];
  __shared__ float sArow[16][204];
  int t = threadIdx.x;
  {
    const ushort* tabs[4] = {tK16, dK16, tV16, dV16};
    uint* dsts[4] = {tKs, dKs, tVs, dVs};
#pragma unroll
    for (int tb = 0; tb < 4; ++tb) {
      const ushort* s = tabs[tb] + h * HSc;
      uint* d = dsts[tb];
      for (int i = t; i < 257 * 8; i += 1024) {
        int r = i >> 3, c = (i & 7) * 8;       // halves within the 64-wide slice
        uint4 v = *(const uint4*)&s[r * Hc + c];
        *(uint4*)&d[r * TROW + (c >> 1)] = v;
      }
    }
  }
  __syncthreads();
  int wave = t >> 6, lane = t & 63;
  int z = h * 4 + b;
  int q = wave * 16 + bz;
  if (q >= Lc) return;
  int m = b * Lc + q;
  int oi = m * Hc + h * HSc + lane;
  if (logs[m] == 0) { seqs[oi] = Qn[oi]; return; }
  const int* tmr = tm + rl(m * Lc);
  const int* dmr = dm + rl(m * Lc);
  // ---- score phase ----
  const uint* Qr = Q16 + rl(m * (Hc / 2) + h * (HSc / 2));
  uint qreg[32];
#pragma unroll
  for (int u = 0; u < 32; ++u) qreg[u] = Qr[u];
  int np = (q >> 6) + 1;
  float sv[4];
  float mx = neg_fill();
#pragma unroll
  for (int p = 0; p < 4; ++p) {
    sv[p] = neg_fill();
    if (p >= np) continue;
    int k = p * 64 + lane;
    int kc = (k <= q) ? k : q;
    int ti = tmr[kc], di = dmr[kc];
    const uint2* tr = (const uint2*)&tKs[ti * TROW];
    const uint2* dr = (const uint2*)&dKs[di * TROW];
    const uint4* Kr = (const uint4*)&K16[(b * Lc + kc) * (Hc / 2) + h * (HSc / 2)];
    float a0 = 0.f, a1 = 0.f;
#pragma unroll
    for (int u = 0; u < 8; ++u) {
      uint4 kv = Kr[u];
      uint2 tv0 = tr[2 * u], tv1 = tr[2 * u + 1];
      uint2 dv0 = dr[2 * u], dv1 = dr[2 * u + 1];
      a0 = dot2(qreg[4 * u + 0], kv.x, a0);  a1 = dot2(qreg[4 * u + 1], kv.y, a1);
      a0 = dot2(qreg[4 * u + 2], kv.z, a0);  a1 = dot2(qreg[4 * u + 3], kv.w, a1);
      a0 = dot2(qreg[4 * u + 0], tv0.x, a0); a1 = dot2(qreg[4 * u + 1], tv0.y, a1);
      a0 = dot2(qreg[4 * u + 2], tv1.x, a0); a1 = dot2(qreg[4 * u + 3], tv1.y, a1);
      a0 = dot2(qreg[4 * u + 0], dv0.x, a0); a1 = dot2(qreg[4 * u + 1], dv0.y, a1);
      a0 = dot2(qreg[4 * u + 2], dv1.x, a0); a1 = dot2(qreg[4 * u + 3], dv1.y, a1);
    }
    if (k <= q) sv[p] = (a0 + a1) * 0.125f;
    mx = fmaxf(mx, sv[p]);
  }
#pragma unroll
  for (int o = 32; o; o >>= 1) mx = fmaxf(mx, __shfl_xor(mx, o));
  float sum = 0.f;
  float ev[4];
#pragma unroll
  for (int p = 0; p < 4; ++p) {
    ev[p] = __expf(sv[p] - mx);
    sum += ev[p];
  }
#pragma unroll
  for (int o = 32; o; o >>= 1) sum += __shfl_xor(sum, o);
  float rs = 1.f / sum;
#pragma unroll
  for (int p = 0; p < 4; ++p) {
    if (p >= np) continue;
    int k = p * 64 + lane;
    if (k < Lc) sArow[wave][k] = ev[p] * rs;
  }
  // zero-pad A row beyond q (read by the paired loop)
  for (int k = q + 1 + lane; k < 204; k += 64) sArow[wave][k] = 0.f;
  // ---- output phase: lanes 0-31 take even k, 32-63 odd k; each lane a d-pair
  int half = lane >> 5, li = lane & 31;
  const uint* Vu = (const uint*)V16 + rl(b * Lc * (Hc / 2) + h * (HSc / 2)) + li;
  float acc0 = 0.f, acc1 = 0.f, acc2 = 0.f, acc3 = 0.f;
  for (int k0 = 0; k0 <= q; k0 += 4) {
    int ka = k0 + half;
    int kb = k0 + 2 + half;
    int kca = (ka <= q) ? ka : q;
    int kcb = (kb <= q) ? kb : q;
    float aa = sArow[wave][ka];
    float ab = sArow[wave][kb];
    int ti0 = tmr[kca], di0 = dmr[kca];
    int ti1 = tmr[kcb], di1 = dmr[kcb];
    uint tv0 = tVs[ti0 * TROW + li];
    uint dv0 = dVs[di0 * TROW + li];
    uint vv0 = Vu[kca * (Hc / 2)];
    uint tv1 = tVs[ti1 * TROW + li];
    uint dv1 = dVs[di1 * TROW + li];
    uint vv1 = Vu[kcb * (Hc / 2)];
    h2 s0 = u2h(tv0) + u2h(dv0) + u2h(vv0);
    h2 s1 = u2h(tv1) + u2h(dv1) + u2h(vv1);
    acc0 = fmaf(aa, (float)s0.x, acc0);
    acc1 = fmaf(aa, (float)s0.y, acc1);
    acc2 = fmaf(ab, (float)s1.x, acc2);
    acc3 = fmaf(ab, (float)s1.y, acc3);
  }
  float accLo = acc0 + acc2; accLo += __shfl_xor(accLo, 32);
  float accHi = acc1 + acc3; accHi += __shfl_xor(accHi, 32);
  if (half == 0) {
    int oib = m * Hc + h * HSc + 2 * li;
    float2 qv = *(const float2*)&Qn[oib];
    float2 r;
    r.x = qv.x + accLo;
    r.y = qv.y + accHi;
    *(float2*)&seqs[oib] = r;
  }
}

// ---------------- fused LN2 + FFN1(relu) + FFN2 + residual + keep ----------
__global__ __launch_bounds__(512)
void ffn_k(float* __restrict__ seqs,
           const float* __restrict__ g, const float* __restrict__ bt,
           const ushort* __restrict__ W1_16, const float* __restrict__ b1,
           const ushort* __restrict__ W2_16, const float* __restrict__ b2,
           const int* __restrict__ logs) {
  __shared__ __fp16 Xl[16][LDH];
  __shared__ __fp16 Hl[16][LDH];
  __shared__ __fp16 Wl[128][LDH];
  int m0 = blockIdx.x * 16;
  int t = threadIdx.x;
  {
    int r = t >> 5, c0 = (t & 31) * 8;
    const float* xr = &seqs[(m0 + r) * Hc + c0];
    float4 v0 = *(const float4*)&xr[0];
    float4 v1 = *(const float4*)&xr[4];
    float s = v0.x + v0.y + v0.z + v0.w + v1.x + v1.y + v1.z + v1.w;
    float q = v0.x*v0.x + v0.y*v0.y + v0.z*v0.z + v0.w*v0.w
            + v1.x*v1.x + v1.y*v1.y + v1.z*v1.z + v1.w*v1.w;
#pragma unroll
    for (int o = 1; o < 32; o <<= 1) { s += __shfl_xor(s, o); q += __shfl_xor(q, o); }
    float mean = s * (1.f / Hc);
    float var = q * (1.f / Hc) - mean * mean;
    float rstd = 1.f / sqrtf(var + 1e-8f);
    float tmp[8] = {v0.x,v0.y,v0.z,v0.w,v1.x,v1.y,v1.z,v1.w};
    float nv[8];
#pragma unroll
    for (int j = 0; j < 8; ++j)
      nv[j] = (tmp[j] - mean) * rstd * g[c0 + j] + bt[c0 + j];
#pragma unroll
    for (int j = 0; j < 8; j += 2)
      *(h2*)&Xl[r][c0 + j] = __builtin_amdgcn_cvt_pkrtz(nv[j], nv[j + 1]);
  }
  int wave = t >> 6, lane = t & 63;
  int row = lane & 15, kg = lane >> 4;
#pragma unroll
  for (int ch = 0; ch < 2; ++ch) {
    __syncthreads();
    for (int i = t; i < 4096; i += 512) {
      int r = i >> 5, c = (i & 31) * 8;
      uint4 v = *(const uint4*)&W1_16[(ch * 128 + r) * Hc + c];
      *(uint4*)&Wl[r][c] = v;
    }
    __syncthreads();
    int bn = wave * 16 + row;
    f32x4 acc = {0.f, 0.f, 0.f, 0.f};
#pragma unroll
    for (int k0 = 0; k0 < Hc; k0 += 32) {
      int kk = k0 + kg * 8;
      f16x8 a = *(const f16x8*)&Xl[row][kk];
      f16x8 bb = *(const f16x8*)&Wl[bn][kk];
      acc = __builtin_amdgcn_mfma_f32_16x16x32_f16(a, bb, acc, 0, 0, 0);
    }
    int coln = ch * 128 + wave * 16 + row;
    float bv = b1[coln];
#pragma unroll
    for (int r = 0; r < 4; ++r) {
      float v = fmaxf(acc[r] + bv, 0.f);
      Hl[kg * 4 + r][coln] = (_Float16)v;
    }
  }
#pragma unroll
  for (int ch = 0; ch < 2; ++ch) {
    __syncthreads();
    for (int i = t; i < 4096; i += 512) {
      int r = i >> 5, c = (i & 31) * 8;
      uint4 v = *(const uint4*)&W2_16[(ch * 128 + r) * Hc + c];
      *(uint4*)&Wl[r][c] = v;
    }
    __syncthreads();
    int bn = wave * 16 + row;
    f32x4 acc = {0.f, 0.f, 0.f, 0.f};
#pragma unroll
    for (int k0 = 0; k0 < Hc; k0 += 32) {
      int kk = k0 + kg * 8;
      f16x8 a = *(const f16x8*)&Hl[row][kk];
      f16x8 bb = *(const f16x8*)&Wl[bn][kk];
      acc = __builtin_amdgcn_mfma_f32_16x16x32_f16(a, bb, acc, 0, 0, 0);
    }
    int coln = ch * 128 + wave * 16 + row;
    float bv = b2[coln];
#pragma unroll
    for (int r = 0; r < 4; ++r) {
      int mrow = kg * 4 + r;
      int m = m0 + mrow;
      float keep = (logs[m] != 0) ? 1.f : 0.f;
      float xv = h2f(__builtin_bit_cast(ushort, Xl[mrow][coln]));
      seqs[m * Hc + coln] = (acc[r] + bv + xv) * keep;
    }
  }
}

extern "C" void kernel_launch(void* const* d_in, const int* in_sizes, int n_in,
                              void* d_out, int out_size, void* d_ws, size_t ws_size,
                              hipStream_t stream) {
  const int* logs = (const int*)d_in[0];
  const int* tm   = (const int*)d_in[1];
  const int* dm   = (const int*)d_in[2];
  const float* item = (const float*)d_in[3];
  const float* pK = (const float*)d_in[4];
  const float* pV = (const float*)d_in[5];
  const float* tK = (const float*)d_in[6];
  const float* tV = (const float*)d_in[7];
  const float* dK = (const float*)d_in[8];
  const float* dV = (const float*)d_in[9];
  const float* ln1_g = (const float*)d_in[10];
  const float* ln1_b = (const float*)d_in[11];
  const float* Wq = (const float*)d_in[12];
  const float* bq = (const float*)d_in[13];
  const float* Wk = (const float*)d_in[14];
  const float* bk = (const float*)d_in[15];
  const float* Wv = (const float*)d_in[16];
  const float* bv = (const float*)d_in[17];
  const float* ln2_g = (const float*)d_in[18];
  const float* ln2_b = (const float*)d_in[19];
  const float* W1 = (const float*)d_in[20];
  const float* b1 = (const float*)d_in[21];
  const float* W2 = (const float*)d_in[22];
  const float* b2 = (const float*)d_in[23];
  const float* lnf_g = (const float*)d_in[24];
  const float* lnf_b = (const float*)d_in[25];

  const int NROW = Mtot * Hc;          // 204800 floats
  float* ws = (float*)d_ws;
  float* sSeqs = ws + 0 * NROW;
  float* sQn   = ws + 1 * NROW;
  ushort* Q16  = (ushort*)(ws + 2 * NROW);
  ushort* K16  = Q16 + NROW;
  ushort* V16  = K16 + NROW;
  ushort* w16  = (ushort*)(ws + 4 * NROW);   // 5*WN + 4*TN halves
  ushort* wq16 = w16 + 0 * WN;
  ushort* wk16 = w16 + 1 * WN;
  ushort* wv16 = w16 + 2 * WN;
  ushort* w116 = w16 + 3 * WN;
  ushort* w216 = w16 + 4 * WN;
  ushort* tK16 = w16 + 5 * WN;
  ushort* tV16 = tK16 + TN;
  ushort* dK16 = tV16 + TN;
  ushort* dV16 = dK16 + TN;

  dim3 gC(64, 9);
  cvtw_k<<<gC, 256, 0, stream>>>(Wq, Wk, Wv, W1, W2, tK, tV, dK, dV, w16);
  embed_k<<<NROW / 256, 256, 0, stream>>>(logs, item, sSeqs);

  dim3 gQKV(Mtot / 16, 12);
  dim3 ga(NHc, Bc, 16);
  const int HHh = Hc * Hc;   // per-layer halves offset in weight arrays
  for (int i = 0; i < NBc; ++i) {
    mmqkv_k<<<gQKV, 256, 0, stream>>>(sSeqs, ln1_g + i * Hc, ln1_b + i * Hc,
                                      wq16 + i * HHh, wk16 + i * HHh, wv16 + i * HHh,
                                      bq + i * Hc, bk + i * Hc, bv + i * Hc,
                                      pK, pV, sQn, Q16, K16, V16);
    attn_k<<<ga, 1024, 0, stream>>>((const uint*)Q16, (const uint*)K16, V16,
                                    tK16, dK16, tV16, dV16,
                                    tm, dm, logs, sQn, sSeqs);
    ffn_k<<<Mtot / 16, 512, 0, stream>>>(sSeqs, ln2_g + i * Hc, ln2_b + i * Hc,
                                         w116 + i * HHh, b1 + i * Hc,
                                         w216 + i * HHh, b2 + i * Hc, logs);
  }
  ln_k<<<Mtot, Hc, 0, stream>>>(sSeqs, lnf_g, lnf_b, (float*)d_out);
}

// Round 10
// 82.817 us; speedup vs baseline: 6.1820x; 1.0518x over previous
//
#include <hip/hip_runtime.h>
#include <math.h>

typedef __fp16 h2 __attribute__((ext_vector_type(2)));
typedef __fp16 f16x8 __attribute__((ext_vector_type(8)));
typedef float f32x4 __attribute__((ext_vector_type(4)));

#define Bc 4
#define Lc 200
#define Hc 256
#define NHc 4
#define HSc 64
#define NBc 2
#define Mtot (Bc*Lc)   // 800
#define TROW 34        // LDS table row stride in u32 (68 halfs = 136B)
#define LDH 264        // mm LDS row stride in halves (528B)
#define WN (2*Hc*Hc)   // 131072 halves per weight array (both layers)
#define TN (257*Hc)    // 65792 halves per table

static __device__ __forceinline__ float neg_fill() { return -4294967295.0f; }
static __device__ __forceinline__ int rl(int x) { return __builtin_amdgcn_readfirstlane(x); }

static __device__ __forceinline__ uint pkh2(float a, float b) {
  h2 r = __builtin_amdgcn_cvt_pkrtz(a, b);
  return __builtin_bit_cast(uint, r);
}
static __device__ __forceinline__ h2 u2h(uint u) { return __builtin_bit_cast(h2, u); }
#if __has_builtin(__builtin_amdgcn_fdot2)
static __device__ __forceinline__ float dot2(uint a, uint b, float c) {
  return __builtin_amdgcn_fdot2(u2h(a), u2h(b), c, false);
}
#else
static __device__ __forceinline__ float dot2(uint a, uint b, float c) {
  h2 x = u2h(a), y = u2h(b);
  return c + (float)x.x * (float)y.x + (float)x.y * (float)y.y;
}
#endif
static __device__ __forceinline__ float h2f(ushort u) {
  return (float)__builtin_bit_cast(_Float16, u);
}

// ---------------- one-shot f32 -> f16 conversion of weights & tables --------
__global__ void cvtw_k(const float* __restrict__ Wq, const float* __restrict__ Wk,
                       const float* __restrict__ Wv, const float* __restrict__ W1,
                       const float* __restrict__ W2,
                       const float* __restrict__ tK, const float* __restrict__ tV,
                       const float* __restrict__ dK, const float* __restrict__ dV,
                       ushort* __restrict__ out) {
  int y = blockIdx.y;
  const float* src;
  int n, off;
  if (y < 5) {
    n = WN; off = y * WN;
    src = (y == 0) ? Wq : (y == 1) ? Wk : (y == 2) ? Wv : (y == 3) ? W1 : W2;
  } else {
    n = TN; off = 5 * WN + (y - 5) * TN;
    src = (y == 5) ? tK : (y == 6) ? tV : (y == 7) ? dK : dV;
  }
  int idx = (blockIdx.x * 256 + threadIdx.x) * 8;
  if (idx >= n) return;
  float4 a = *(const float4*)&src[idx];
  float4 b = *(const float4*)&src[idx + 4];
  uint4 o;
  o.x = pkh2(a.x, a.y); o.y = pkh2(a.z, a.w);
  o.z = pkh2(b.x, b.y); o.w = pkh2(b.z, b.w);
  *(uint4*)&out[off + idx] = o;
}

// ---------------- fused [embed+] LN1 + QKV projections (f16 weights) --------
// grid (50, 12): y>>2 = region (0=Q,1=K,2=V), y&3 -> n-chunk of 64.
// useEmb: source activation rows from item_embs[logs[m]] (layer 0) vs seqs.
__global__ __launch_bounds__(256)
void mmqkv_k(const float* __restrict__ seqs, const float* __restrict__ emb,
             const int* __restrict__ logs, int useEmb,
             const float* __restrict__ g, const float* __restrict__ bt,
             const ushort* __restrict__ Wq16, const ushort* __restrict__ Wk16,
             const ushort* __restrict__ Wv16,
             const float* __restrict__ bq, const float* __restrict__ bk,
             const float* __restrict__ bv,
             const float* __restrict__ pK, const float* __restrict__ pV,
             float* __restrict__ Qn,
             ushort* __restrict__ Q16, ushort* __restrict__ K16,
             ushort* __restrict__ V16) {
  __shared__ __fp16 Al[16][LDH];
  __shared__ __fp16 Wl[64][LDH];
  int m0 = blockIdx.x * 16;
  int y = blockIdx.y;
  int region = y >> 2, nloc = (y & 3) * 64;
  const ushort* Wsrc = (region == 0) ? Wq16 : (region == 1 ? Wk16 : Wv16);
  const float* bias = (region == 0) ? bq : (region == 1 ? bk : bv);
  int t = threadIdx.x;
  if (region == 0) {
    int r = t >> 4, c0 = (t & 15) * 16;
    int m = m0 + r;
    const float* xr;
    bool zero = false;
    if (useEmb) {
      int tok = logs[m];
      zero = (tok == 0);
      xr = &emb[tok * Hc + c0];
    } else {
      xr = &seqs[m * Hc + c0];
    }
    float4 v0, v1, v2, v3;
    if (zero) {
      v0 = v1 = v2 = v3 = make_float4(0.f, 0.f, 0.f, 0.f);
    } else {
      v0 = *(const float4*)&xr[0];
      v1 = *(const float4*)&xr[4];
      v2 = *(const float4*)&xr[8];
      v3 = *(const float4*)&xr[12];
    }
    float s = v0.x + v0.y + v0.z + v0.w + v1.x + v1.y + v1.z + v1.w
            + v2.x + v2.y + v2.z + v2.w + v3.x + v3.y + v3.z + v3.w;
    float q = v0.x*v0.x + v0.y*v0.y + v0.z*v0.z + v0.w*v0.w
            + v1.x*v1.x + v1.y*v1.y + v1.z*v1.z + v1.w*v1.w
            + v2.x*v2.x + v2.y*v2.y + v2.z*v2.z + v2.w*v2.w
            + v3.x*v3.x + v3.y*v3.y + v3.z*v3.z + v3.w*v3.w;
#pragma unroll
    for (int o = 1; o < 16; o <<= 1) { s += __shfl_xor(s, o); q += __shfl_xor(q, o); }
    float mean = s * (1.f / Hc);
    float var = q * (1.f / Hc) - mean * mean;
    float rstd = 1.f / sqrtf(var + 1e-8f);
    float tmp[16] = {v0.x,v0.y,v0.z,v0.w,v1.x,v1.y,v1.z,v1.w,
                     v2.x,v2.y,v2.z,v2.w,v3.x,v3.y,v3.z,v3.w};
    float nv[16];
#pragma unroll
    for (int j = 0; j < 16; ++j)
      nv[j] = (tmp[j] - mean) * rstd * g[c0 + j] + bt[c0 + j];
#pragma unroll
    for (int j = 0; j < 16; j += 2)
      *(h2*)&Al[r][c0 + j] = __builtin_amdgcn_cvt_pkrtz(nv[j], nv[j + 1]);
    if (y == 0) {
#pragma unroll
      for (int j = 0; j < 16; j += 4)
        *(float4*)&Qn[m * Hc + c0 + j] = make_float4(nv[j], nv[j+1], nv[j+2], nv[j+3]);
    }
  } else {
    for (int i = t; i < 16 * 64; i += 256) {
      int r = i >> 6, c = (i & 63) * 4;
      int m = m0 + r;
      float4 v;
      if (useEmb) {
        int tok = logs[m];
        v = (tok == 0) ? make_float4(0.f, 0.f, 0.f, 0.f)
                       : *(const float4*)&emb[tok * Hc + c];
      } else {
        v = *(const float4*)&seqs[m * Hc + c];
      }
      *(h2*)&Al[r][c] = __builtin_amdgcn_cvt_pkrtz(v.x, v.y);
      *(h2*)&Al[r][c + 2] = __builtin_amdgcn_cvt_pkrtz(v.z, v.w);
    }
  }
  for (int i = t; i < 2048; i += 256) {
    int r = i >> 5, c = (i & 31) * 8;
    uint4 v = *(const uint4*)&Wsrc[(nloc + r) * Hc + c];
    *(uint4*)&Wl[r][c] = v;
  }
  __syncthreads();
  int wave = t >> 6, lane = t & 63;
  int row = lane & 15, kg = lane >> 4;
  int bn = wave * 16 + row;
  f32x4 acc = {0.f, 0.f, 0.f, 0.f};
#pragma unroll
  for (int k0 = 0; k0 < Hc; k0 += 32) {
    int kk = k0 + kg * 8;
    f16x8 a = *(const f16x8*)&Al[row][kk];
    f16x8 bb = *(const f16x8*)&Wl[bn][kk];
    acc = __builtin_amdgcn_mfma_f32_16x16x32_f16(a, bb, acc, 0, 0, 0);
  }
  int coln = nloc + wave * 16 + row;
  ushort* op = (region == 0) ? Q16 : (region == 1 ? K16 : V16);
  const float* pT = (region == 1) ? pK : pV;
#pragma unroll
  for (int r = 0; r < 4; ++r) {
    int m = m0 + kg * 4 + r;
    float v = acc[r] + bias[coln];
    if (region) v += pT[(m % Lc) * Hc + coln];
    op[m * Hc + coln] = __builtin_bit_cast(ushort, (_Float16)v);
  }
}

// ---------------- fused attention (f16 tables; paired-k out phase) ----------
__global__ __launch_bounds__(1024, 4)
void attn_k(const uint* __restrict__ Q16, const uint* __restrict__ K16,
            const ushort* __restrict__ V16,
            const ushort* __restrict__ tK16, const ushort* __restrict__ dK16,
            const ushort* __restrict__ tV16, const ushort* __restrict__ dV16,
            const int* __restrict__ tm, const int* __restrict__ dm,
            const int* __restrict__ logs,
            const float* __restrict__ Qn, float* __restrict__ seqs) {
  int h = blockIdx.x, b = blockIdx.y, bz = blockIdx.z;
  __shared__ uint tKs[257 * TROW];
  __shared__ uint dKs[257 * TROW];
  __shared__ uint tVs[257 * TROW];
  __shared__ uint dVs[257 * TROW];
  __shared__ float sArow[16][204];
  int t = threadIdx.x;
  {
    const ushort* tabs[4] = {tK16, dK16, tV16, dV16};
    uint* dsts[4] = {tKs, dKs, tVs, dVs};
#pragma unroll
    for (int tb = 0; tb < 4; ++tb) {
      const ushort* s = tabs[tb] + h * HSc;
      uint* d = dsts[tb];
      for (int i = t; i < 257 * 8; i += 1024) {
        int r = i >> 3, c = (i & 7) * 8;
        uint4 v = *(const uint4*)&s[r * Hc + c];
        *(uint4*)&d[r * TROW + (c >> 1)] = v;
      }
    }
  }
  __syncthreads();
  int wave = t >> 6, lane = t & 63;
  int z = h * 4 + b;
  int q = wave * 16 + bz;
  if (q >= Lc) return;
  int m = b * Lc + q;
  int oi = m * Hc + h * HSc + lane;
  if (logs[m] == 0) { seqs[oi] = Qn[oi]; return; }
  const int* tmr = tm + rl(m * Lc);
  const int* dmr = dm + rl(m * Lc);
  const uint* Qr = Q16 + rl(m * (Hc / 2) + h * (HSc / 2));
  uint qreg[32];
#pragma unroll
  for (int u = 0; u < 32; ++u) qreg[u] = Qr[u];
  int np = (q >> 6) + 1;
  float sv[4];
  float mx = neg_fill();
#pragma unroll
  for (int p = 0; p < 4; ++p) {
    sv[p] = neg_fill();
    if (p >= np) continue;
    int k = p * 64 + lane;
    int kc = (k <= q) ? k : q;
    int ti = tmr[kc], di = dmr[kc];
    const uint2* tr = (const uint2*)&tKs[ti * TROW];
    const uint2* dr = (const uint2*)&dKs[di * TROW];
    const uint4* Kr = (const uint4*)&K16[(b * Lc + kc) * (Hc / 2) + h * (HSc / 2)];
    float a0 = 0.f, a1 = 0.f;
#pragma unroll
    for (int u = 0; u < 8; ++u) {
      uint4 kv = Kr[u];
      uint2 tv0 = tr[2 * u], tv1 = tr[2 * u + 1];
      uint2 dv0 = dr[2 * u], dv1 = dr[2 * u + 1];
      a0 = dot2(qreg[4 * u + 0], kv.x, a0);  a1 = dot2(qreg[4 * u + 1], kv.y, a1);
      a0 = dot2(qreg[4 * u + 2], kv.z, a0);  a1 = dot2(qreg[4 * u + 3], kv.w, a1);
      a0 = dot2(qreg[4 * u + 0], tv0.x, a0); a1 = dot2(qreg[4 * u + 1], tv0.y, a1);
      a0 = dot2(qreg[4 * u + 2], tv1.x, a0); a1 = dot2(qreg[4 * u + 3], tv1.y, a1);
      a0 = dot2(qreg[4 * u + 0], dv0.x, a0); a1 = dot2(qreg[4 * u + 1], dv0.y, a1);
      a0 = dot2(qreg[4 * u + 2], dv1.x, a0); a1 = dot2(qreg[4 * u + 3], dv1.y, a1);
    }
    if (k <= q) sv[p] = (a0 + a1) * 0.125f;
    mx = fmaxf(mx, sv[p]);
  }
#pragma unroll
  for (int o = 32; o; o >>= 1) mx = fmaxf(mx, __shfl_xor(mx, o));
  float sum = 0.f;
  float ev[4];
#pragma unroll
  for (int p = 0; p < 4; ++p) {
    ev[p] = __expf(sv[p] - mx);
    sum += ev[p];
  }
#pragma unroll
  for (int o = 32; o; o >>= 1) sum += __shfl_xor(sum, o);
  float rs = 1.f / sum;
#pragma unroll
  for (int p = 0; p < 4; ++p) {
    if (p >= np) continue;
    int k = p * 64 + lane;
    if (k < Lc) sArow[wave][k] = ev[p] * rs;
  }
  for (int k = q + 1 + lane; k < 204; k += 64) sArow[wave][k] = 0.f;
  int half = lane >> 5, li = lane & 31;
  const uint* Vu = (const uint*)V16 + rl(b * Lc * (Hc / 2) + h * (HSc / 2)) + li;
  float acc0 = 0.f, acc1 = 0.f, acc2 = 0.f, acc3 = 0.f;
  for (int k0 = 0; k0 <= q; k0 += 4) {
    int ka = k0 + half;
    int kb = k0 + 2 + half;
    int kca = (ka <= q) ? ka : q;
    int kcb = (kb <= q) ? kb : q;
    float aa = sArow[wave][ka];
    float ab = sArow[wave][kb];
    int ti0 = tmr[kca], di0 = dmr[kca];
    int ti1 = tmr[kcb], di1 = dmr[kcb];
    uint tv0 = tVs[ti0 * TROW + li];
    uint dv0 = dVs[di0 * TROW + li];
    uint vv0 = Vu[kca * (Hc / 2)];
    uint tv1 = tVs[ti1 * TROW + li];
    uint dv1 = dVs[di1 * TROW + li];
    uint vv1 = Vu[kcb * (Hc / 2)];
    h2 s0 = u2h(tv0) + u2h(dv0) + u2h(vv0);
    h2 s1 = u2h(tv1) + u2h(dv1) + u2h(vv1);
    acc0 = fmaf(aa, (float)s0.x, acc0);
    acc1 = fmaf(aa, (float)s0.y, acc1);
    acc2 = fmaf(ab, (float)s1.x, acc2);
    acc3 = fmaf(ab, (float)s1.y, acc3);
  }
  float accLo = acc0 + acc2; accLo += __shfl_xor(accLo, 32);
  float accHi = acc1 + acc3; accHi += __shfl_xor(accHi, 32);
  if (half == 0) {
    int oib = m * Hc + h * HSc + 2 * li;
    float2 qv = *(const float2*)&Qn[oib];
    float2 r;
    r.x = qv.x + accLo;
    r.y = qv.y + accHi;
    *(float2*)&seqs[oib] = r;
  }
}

// ---------------- fused LN2 + FFN1(relu) + FFN2 + residual + keep [+ lnf] ---
// FIN=1: apply final layernorm and write f32 d_out instead of seqs.
template <int FIN>
__global__ __launch_bounds__(512)
void ffn_k(float* __restrict__ seqs,
           const float* __restrict__ g, const float* __restrict__ bt,
           const ushort* __restrict__ W1_16, const float* __restrict__ b1,
           const ushort* __restrict__ W2_16, const float* __restrict__ b2,
           const int* __restrict__ logs,
           const float* __restrict__ lnf_g, const float* __restrict__ lnf_b,
           float* __restrict__ dout) {
  __shared__ __fp16 Xl[16][LDH];
  __shared__ __fp16 Hl[16][LDH];
  __shared__ __fp16 Wl[128][LDH];
  __shared__ float Ol[16][Hc];
  int m0 = blockIdx.x * 16;
  int t = threadIdx.x;
  {
    int r = t >> 5, c0 = (t & 31) * 8;
    const float* xr = &seqs[(m0 + r) * Hc + c0];
    float4 v0 = *(const float4*)&xr[0];
    float4 v1 = *(const float4*)&xr[4];
    float s = v0.x + v0.y + v0.z + v0.w + v1.x + v1.y + v1.z + v1.w;
    float q = v0.x*v0.x + v0.y*v0.y + v0.z*v0.z + v0.w*v0.w
            + v1.x*v1.x + v1.y*v1.y + v1.z*v1.z + v1.w*v1.w;
#pragma unroll
    for (int o = 1; o < 32; o <<= 1) { s += __shfl_xor(s, o); q += __shfl_xor(q, o); }
    float mean = s * (1.f / Hc);
    float var = q * (1.f / Hc) - mean * mean;
    float rstd = 1.f / sqrtf(var + 1e-8f);
    float tmp[8] = {v0.x,v0.y,v0.z,v0.w,v1.x,v1.y,v1.z,v1.w};
    float nv[8];
#pragma unroll
    for (int j = 0; j < 8; ++j)
      nv[j] = (tmp[j] - mean) * rstd * g[c0 + j] + bt[c0 + j];
#pragma unroll
    for (int j = 0; j < 8; j += 2)
      *(h2*)&Xl[r][c0 + j] = __builtin_amdgcn_cvt_pkrtz(nv[j], nv[j + 1]);
  }
  int wave = t >> 6, lane = t & 63;
  int row = lane & 15, kg = lane >> 4;
#pragma unroll
  for (int ch = 0; ch < 2; ++ch) {
    __syncthreads();
    for (int i = t; i < 4096; i += 512) {
      int r = i >> 5, c = (i & 31) * 8;
      uint4 v = *(const uint4*)&W1_16[(ch * 128 + r) * Hc + c];
      *(uint4*)&Wl[r][c] = v;
    }
    __syncthreads();
    int bn = wave * 16 + row;
    f32x4 acc = {0.f, 0.f, 0.f, 0.f};
#pragma unroll
    for (int k0 = 0; k0 < Hc; k0 += 32) {
      int kk = k0 + kg * 8;
      f16x8 a = *(const f16x8*)&Xl[row][kk];
      f16x8 bb = *(const f16x8*)&Wl[bn][kk];
      acc = __builtin_amdgcn_mfma_f32_16x16x32_f16(a, bb, acc, 0, 0, 0);
    }
    int coln = ch * 128 + wave * 16 + row;
    float bv = b1[coln];
#pragma unroll
    for (int r = 0; r < 4; ++r) {
      float v = fmaxf(acc[r] + bv, 0.f);
      Hl[kg * 4 + r][coln] = (_Float16)v;
    }
  }
#pragma unroll
  for (int ch = 0; ch < 2; ++ch) {
    __syncthreads();
    for (int i = t; i < 4096; i += 512) {
      int r = i >> 5, c = (i & 31) * 8;
      uint4 v = *(const uint4*)&W2_16[(ch * 128 + r) * Hc + c];
      *(uint4*)&Wl[r][c] = v;
    }
    __syncthreads();
    int bn = wave * 16 + row;
    f32x4 acc = {0.f, 0.f, 0.f, 0.f};
#pragma unroll
    for (int k0 = 0; k0 < Hc; k0 += 32) {
      int kk = k0 + kg * 8;
      f16x8 a = *(const f16x8*)&Hl[row][kk];
      f16x8 bb = *(const f16x8*)&Wl[bn][kk];
      acc = __builtin_amdgcn_mfma_f32_16x16x32_f16(a, bb, acc, 0, 0, 0);
    }
    int coln = ch * 128 + wave * 16 + row;
    float bv = b2[coln];
#pragma unroll
    for (int r = 0; r < 4; ++r) {
      int mrow = kg * 4 + r;
      int m = m0 + mrow;
      float keep = (logs[m] != 0) ? 1.f : 0.f;
      float xv = h2f(__builtin_bit_cast(ushort, Xl[mrow][coln]));
      float val = (acc[r] + bv + xv) * keep;
      if (FIN) Ol[mrow][coln] = val;
      else     seqs[m * Hc + coln] = val;
    }
  }
  if (FIN) {
    __syncthreads();
    int r = t >> 5, c0 = (t & 31) * 8;
    float v[8];
#pragma unroll
    for (int j = 0; j < 8; ++j) v[j] = Ol[r][c0 + j];
    float s = 0.f, q = 0.f;
#pragma unroll
    for (int j = 0; j < 8; ++j) { s += v[j]; q += v[j] * v[j]; }
#pragma unroll
    for (int o = 1; o < 32; o <<= 1) { s += __shfl_xor(s, o); q += __shfl_xor(q, o); }
    float mean = s * (1.f / Hc);
    float var = q * (1.f / Hc) - mean * mean;
    float rstd = 1.f / sqrtf(var + 1e-8f);
#pragma unroll
    for (int j = 0; j < 8; ++j)
      dout[(m0 + r) * Hc + c0 + j] = (v[j] - mean) * rstd * lnf_g[c0 + j] + lnf_b[c0 + j];
  }
}

extern "C" void kernel_launch(void* const* d_in, const int* in_sizes, int n_in,
                              void* d_out, int out_size, void* d_ws, size_t ws_size,
                              hipStream_t stream) {
  const int* logs = (const int*)d_in[0];
  const int* tm   = (const int*)d_in[1];
  const int* dm   = (const int*)d_in[2];
  const float* item = (const float*)d_in[3];
  const float* pK = (const float*)d_in[4];
  const float* pV = (const float*)d_in[5];
  const float* tK = (const float*)d_in[6];
  const float* tV = (const float*)d_in[7];
  const float* dK = (const float*)d_in[8];
  const float* dV = (const float*)d_in[9];
  const float* ln1_g = (const float*)d_in[10];
  const float* ln1_b = (const float*)d_in[11];
  const float* Wq = (const float*)d_in[12];
  const float* bq = (const float*)d_in[13];
  const float* Wk = (const float*)d_in[14];
  const float* bk = (const float*)d_in[15];
  const float* Wv = (const float*)d_in[16];
  const float* bv = (const float*)d_in[17];
  const float* ln2_g = (const float*)d_in[18];
  const float* ln2_b = (const float*)d_in[19];
  const float* W1 = (const float*)d_in[20];
  const float* b1 = (const float*)d_in[21];
  const float* W2 = (const float*)d_in[22];
  const float* b2 = (const float*)d_in[23];
  const float* lnf_g = (const float*)d_in[24];
  const float* lnf_b = (const float*)d_in[25];

  const int NROW = Mtot * Hc;          // 204800 floats
  float* ws = (float*)d_ws;
  float* sSeqs = ws + 0 * NROW;
  float* sQn   = ws + 1 * NROW;
  ushort* Q16  = (ushort*)(ws + 2 * NROW);
  ushort* K16  = Q16 + NROW;
  ushort* V16  = K16 + NROW;
  ushort* w16  = (ushort*)(ws + 4 * NROW);   // 5*WN + 4*TN halves
  ushort* wq16 = w16 + 0 * WN;
  ushort* wk16 = w16 + 1 * WN;
  ushort* wv16 = w16 + 2 * WN;
  ushort* w116 = w16 + 3 * WN;
  ushort* w216 = w16 + 4 * WN;
  ushort* tK16 = w16 + 5 * WN;
  ushort* tV16 = tK16 + TN;
  ushort* dK16 = tV16 + TN;
  ushort* dV16 = dK16 + TN;

  dim3 gC(64, 9);
  cvtw_k<<<gC, 256, 0, stream>>>(Wq, Wk, Wv, W1, W2, tK, tV, dK, dV, w16);

  dim3 gQKV(Mtot / 16, 12);
  dim3 ga(NHc, Bc, 16);
  const int HHh = Hc * Hc;
  for (int i = 0; i < NBc; ++i) {
    mmqkv_k<<<gQKV, 256, 0, stream>>>(sSeqs, item, logs, (i == 0) ? 1 : 0,
                                      ln1_g + i * Hc, ln1_b + i * Hc,
                                      wq16 + i * HHh, wk16 + i * HHh, wv16 + i * HHh,
                                      bq + i * Hc, bk + i * Hc, bv + i * Hc,
                                      pK, pV, sQn, Q16, K16, V16);
    attn_k<<<ga, 1024, 0, stream>>>((const uint*)Q16, (const uint*)K16, V16,
                                    tK16, dK16, tV16, dV16,
                                    tm, dm, logs, sQn, sSeqs);
    if (i == 0)
      ffn_k<0><<<Mtot / 16, 512, 0, stream>>>(sSeqs, ln2_g + i * Hc, ln2_b + i * Hc,
                                              w116 + i * HHh, b1 + i * Hc,
                                              w216 + i * HHh, b2 + i * Hc, logs,
                                              nullptr, nullptr, nullptr);
    else
      ffn_k<1><<<Mtot / 16, 512, 0, stream>>>(sSeqs, ln2_g + i * Hc, ln2_b + i * Hc,
                                              w116 + i * HHh, b1 + i * Hc,
                                              w216 + i * HHh, b2 + i * Hc, logs,
                                              lnf_g, lnf_b, (float*)d_out);
  }
}

// Round 11
// 75.885 us; speedup vs baseline: 6.7468x; 1.0914x over previous
//
#include <hip/hip_runtime.h>
#include <math.h>

typedef __fp16 h2 __attribute__((ext_vector_type(2)));
typedef __fp16 f16x8 __attribute__((ext_vector_type(8)));
typedef float f32x4 __attribute__((ext_vector_type(4)));

#define Bc 4
#define Lc 200
#define Hc 256
#define NHc 4
#define HSc 64
#define NBc 2
#define Mtot (Bc*Lc)   // 800
#define TROW 34        // LDS table row stride in u32 (68 halfs = 136B)
#define LDH 264        // mm LDS row stride in halves (528B)
#define WN (2*Hc*Hc)   // 131072 halves per weight array (both layers)
#define TN (257*Hc)    // 65792 halves per table

static __device__ __forceinline__ float neg_fill() { return -4294967295.0f; }
static __device__ __forceinline__ int rl(int x) { return __builtin_amdgcn_readfirstlane(x); }

static __device__ __forceinline__ uint pkh2(float a, float b) {
  h2 r = __builtin_amdgcn_cvt_pkrtz(a, b);
  return __builtin_bit_cast(uint, r);
}
static __device__ __forceinline__ h2 u2h(uint u) { return __builtin_bit_cast(h2, u); }
static __device__ __forceinline__ float h2f(ushort u) {
  return (float)__builtin_bit_cast(_Float16, u);
}

// ---------------- one-shot f32 -> f16 conversion of weights & tables --------
__global__ void cvtw_k(const float* __restrict__ Wq, const float* __restrict__ Wk,
                       const float* __restrict__ Wv, const float* __restrict__ W1,
                       const float* __restrict__ W2,
                       const float* __restrict__ tK, const float* __restrict__ tV,
                       const float* __restrict__ dK, const float* __restrict__ dV,
                       ushort* __restrict__ out) {
  int y = blockIdx.y;
  const float* src;
  int n, off;
  if (y < 5) {
    n = WN; off = y * WN;
    src = (y == 0) ? Wq : (y == 1) ? Wk : (y == 2) ? Wv : (y == 3) ? W1 : W2;
  } else {
    n = TN; off = 5 * WN + (y - 5) * TN;
    src = (y == 5) ? tK : (y == 6) ? tV : (y == 7) ? dK : dV;
  }
  int idx = (blockIdx.x * 256 + threadIdx.x) * 8;
  if (idx >= n) return;
  float4 a = *(const float4*)&src[idx];
  float4 b = *(const float4*)&src[idx + 4];
  uint4 o;
  o.x = pkh2(a.x, a.y); o.y = pkh2(a.z, a.w);
  o.z = pkh2(b.x, b.y); o.w = pkh2(b.z, b.w);
  *(uint4*)&out[off + idx] = o;
}

// ---------------- fused [embed+] LN1 + QKV projections (f16 weights) --------
__global__ __launch_bounds__(256)
void mmqkv_k(const float* __restrict__ seqs, const float* __restrict__ emb,
             const int* __restrict__ logs, int useEmb,
             const float* __restrict__ g, const float* __restrict__ bt,
             const ushort* __restrict__ Wq16, const ushort* __restrict__ Wk16,
             const ushort* __restrict__ Wv16,
             const float* __restrict__ bq, const float* __restrict__ bk,
             const float* __restrict__ bv,
             const float* __restrict__ pK, const float* __restrict__ pV,
             float* __restrict__ Qn,
             ushort* __restrict__ Q16, ushort* __restrict__ K16,
             ushort* __restrict__ V16) {
  __shared__ __fp16 Al[16][LDH];
  __shared__ __fp16 Wl[64][LDH];
  int m0 = blockIdx.x * 16;
  int y = blockIdx.y;
  int region = y >> 2, nloc = (y & 3) * 64;
  const ushort* Wsrc = (region == 0) ? Wq16 : (region == 1 ? Wk16 : Wv16);
  const float* bias = (region == 0) ? bq : (region == 1 ? bk : bv);
  int t = threadIdx.x;
  if (region == 0) {
    int r = t >> 4, c0 = (t & 15) * 16;
    int m = m0 + r;
    const float* xr;
    bool zero = false;
    if (useEmb) {
      int tok = logs[m];
      zero = (tok == 0);
      xr = &emb[tok * Hc + c0];
    } else {
      xr = &seqs[m * Hc + c0];
    }
    float4 v0, v1, v2, v3;
    if (zero) {
      v0 = v1 = v2 = v3 = make_float4(0.f, 0.f, 0.f, 0.f);
    } else {
      v0 = *(const float4*)&xr[0];
      v1 = *(const float4*)&xr[4];
      v2 = *(const float4*)&xr[8];
      v3 = *(const float4*)&xr[12];
    }
    float s = v0.x + v0.y + v0.z + v0.w + v1.x + v1.y + v1.z + v1.w
            + v2.x + v2.y + v2.z + v2.w + v3.x + v3.y + v3.z + v3.w;
    float q = v0.x*v0.x + v0.y*v0.y + v0.z*v0.z + v0.w*v0.w
            + v1.x*v1.x + v1.y*v1.y + v1.z*v1.z + v1.w*v1.w
            + v2.x*v2.x + v2.y*v2.y + v2.z*v2.z + v2.w*v2.w
            + v3.x*v3.x + v3.y*v3.y + v3.z*v3.z + v3.w*v3.w;
#pragma unroll
    for (int o = 1; o < 16; o <<= 1) { s += __shfl_xor(s, o); q += __shfl_xor(q, o); }
    float mean = s * (1.f / Hc);
    float var = q * (1.f / Hc) - mean * mean;
    float rstd = 1.f / sqrtf(var + 1e-8f);
    float tmp[16] = {v0.x,v0.y,v0.z,v0.w,v1.x,v1.y,v1.z,v1.w,
                     v2.x,v2.y,v2.z,v2.w,v3.x,v3.y,v3.z,v3.w};
    float nv[16];
#pragma unroll
    for (int j = 0; j < 16; ++j)
      nv[j] = (tmp[j] - mean) * rstd * g[c0 + j] + bt[c0 + j];
#pragma unroll
    for (int j = 0; j < 16; j += 2)
      *(h2*)&Al[r][c0 + j] = __builtin_amdgcn_cvt_pkrtz(nv[j], nv[j + 1]);
    if (y == 0) {
#pragma unroll
      for (int j = 0; j < 16; j += 4)
        *(float4*)&Qn[m * Hc + c0 + j] = make_float4(nv[j], nv[j+1], nv[j+2], nv[j+3]);
    }
  } else {
    for (int i = t; i < 16 * 64; i += 256) {
      int r = i >> 6, c = (i & 63) * 4;
      int m = m0 + r;
      float4 v;
      if (useEmb) {
        int tok = logs[m];
        v = (tok == 0) ? make_float4(0.f, 0.f, 0.f, 0.f)
                       : *(const float4*)&emb[tok * Hc + c];
      } else {
        v = *(const float4*)&seqs[m * Hc + c];
      }
      *(h2*)&Al[r][c] = __builtin_amdgcn_cvt_pkrtz(v.x, v.y);
      *(h2*)&Al[r][c + 2] = __builtin_amdgcn_cvt_pkrtz(v.z, v.w);
    }
  }
  for (int i = t; i < 2048; i += 256) {
    int r = i >> 5, c = (i & 31) * 8;
    uint4 v = *(const uint4*)&Wsrc[(nloc + r) * Hc + c];
    *(uint4*)&Wl[r][c] = v;
  }
  __syncthreads();
  int wave = t >> 6, lane = t & 63;
  int row = lane & 15, kg = lane >> 4;
  int bn = wave * 16 + row;
  f32x4 acc = {0.f, 0.f, 0.f, 0.f};
#pragma unroll
  for (int k0 = 0; k0 < Hc; k0 += 32) {
    int kk = k0 + kg * 8;
    f16x8 a = *(const f16x8*)&Al[row][kk];
    f16x8 bb = *(const f16x8*)&Wl[bn][kk];
    acc = __builtin_amdgcn_mfma_f32_16x16x32_f16(a, bb, acc, 0, 0, 0);
  }
  int coln = nloc + wave * 16 + row;
  ushort* op = (region == 0) ? Q16 : (region == 1 ? K16 : V16);
  const float* pT = (region == 1) ? pK : pV;
#pragma unroll
  for (int r = 0; r < 4; ++r) {
    int m = m0 + kg * 4 + r;
    float v = acc[r] + bias[coln];
    if (region) v += pT[(m % Lc) * Hc + coln];
    op[m * Hc + coln] = __builtin_bit_cast(ushort, (_Float16)v);
  }
}

// ---------------- fused attention: MFMA scores + softmax + paired-k out -----
// grid (NHc, Bc, 16) = 256 blocks; block 1024 (16 waves), wave w owns q=16w+bz.
// Phase 1 (all waves): S0 = Q.K'^T, Tq = Q.tK^T, Dq = Q.dK^T via MFMA -> LDS.
// Phase 2 (per wave): assemble + softmax + output, as before.
__global__ __launch_bounds__(1024, 4)
void attn_k(const ushort* __restrict__ Q16, const ushort* __restrict__ K16,
            const ushort* __restrict__ V16,
            const ushort* __restrict__ tK16, const ushort* __restrict__ dK16,
            const ushort* __restrict__ tV16, const ushort* __restrict__ dV16,
            const int* __restrict__ tm, const int* __restrict__ dm,
            const int* __restrict__ logs,
            const float* __restrict__ Qn, float* __restrict__ seqs) {
  int h = blockIdx.x, b = blockIdx.y, bz = blockIdx.z;
  __shared__ uint tVs[257 * TROW];
  __shared__ uint dVs[257 * TROW];
  __shared__ float S0l[16][212];
  __shared__ float Tql[16][272];
  __shared__ float Dql[16][272];
  __shared__ float sArow[16][204];
  int t = threadIdx.x;
  int wave = t >> 6, lane = t & 63;
  int row16 = lane & 15, kg = lane >> 4;
  // ---- stage tV/dV (out-phase tables) ----
  {
    const ushort* s1 = tV16 + h * HSc;
    const ushort* s2 = dV16 + h * HSc;
    for (int i = t; i < 257 * 8; i += 1024) {
      int r = i >> 3, c = (i & 7) * 8;
      *(uint4*)&tVs[r * TROW + (c >> 1)] = *(const uint4*)&s1[r * Hc + c];
      *(uint4*)&dVs[r * TROW + (c >> 1)] = *(const uint4*)&s2[r * Hc + c];
    }
  }
  // ---- phase 1: MFMA tile-jobs ----
  {
    int qa = row16 * 16 + bz;               // A-row (strided q of this block)
    bool va = qa < Lc;
    f16x8 A0 = {0,0,0,0,0,0,0,0}, A1 = A0;
    if (va) {
      const ushort* Qr = &Q16[(b * Lc + qa) * Hc + h * HSc];
      A0 = *(const f16x8*)&Qr[kg * 8];
      A1 = *(const f16x8*)&Qr[32 + kg * 8];
    }
    for (int j = wave; j < 47; j += 16) {
      int kind, n;
      if (j < 13) { kind = 0; n = j; }
      else if (j < 30) { kind = 1; n = j - 13; }
      else { kind = 2; n = j - 30; }
      int col = n * 16 + row16;
      const ushort* Bsrc;
      bool vb;
      if (kind == 0) { vb = col < Lc; Bsrc = &K16[(b * Lc + (vb ? col : 0)) * Hc + h * HSc]; }
      else { vb = col < 257; Bsrc = &((kind == 1) ? tK16 : dK16)[(vb ? col : 0) * Hc + h * HSc]; }
      f16x8 B0 = {0,0,0,0,0,0,0,0}, B1 = B0;
      if (vb) {
        B0 = *(const f16x8*)&Bsrc[kg * 8];
        B1 = *(const f16x8*)&Bsrc[32 + kg * 8];
      }
      f32x4 acc = {0.f, 0.f, 0.f, 0.f};
      acc = __builtin_amdgcn_mfma_f32_16x16x32_f16(A0, B0, acc, 0, 0, 0);
      acc = __builtin_amdgcn_mfma_f32_16x16x32_f16(A1, B1, acc, 0, 0, 0);
      if (kind == 0) {
#pragma unroll
        for (int r = 0; r < 4; ++r) S0l[kg * 4 + r][col] = acc[r];
      } else if (kind == 1) {
#pragma unroll
        for (int r = 0; r < 4; ++r) Tql[kg * 4 + r][col] = acc[r];
      } else {
#pragma unroll
        for (int r = 0; r < 4; ++r) Dql[kg * 4 + r][col] = acc[r];
      }
    }
  }
  __syncthreads();
  // ---- phase 2: per-wave score assembly + softmax + output ----
  int q = wave * 16 + bz;
  if (q >= Lc) return;
  int m = b * Lc + q;
  int oi = m * Hc + h * HSc + lane;
  if (logs[m] == 0) { seqs[oi] = Qn[oi]; return; }
  const int* tmr = tm + rl(m * Lc);
  const int* dmr = dm + rl(m * Lc);
  const float* srow = S0l[wave];
  const float* trow = Tql[wave];
  const float* drow = Dql[wave];
  int np = (q >> 6) + 1;
  float sv[4];
  float mx = neg_fill();
#pragma unroll
  for (int p = 0; p < 4; ++p) {
    sv[p] = neg_fill();
    if (p >= np) continue;
    int k = p * 64 + lane;
    int kc = (k <= q) ? k : q;
    int ti = tmr[kc], di = dmr[kc];
    float sc = (srow[kc] + trow[ti] + drow[di]) * 0.125f;
    if (k <= q) sv[p] = sc;
    mx = fmaxf(mx, sv[p]);
  }
#pragma unroll
  for (int o = 32; o; o >>= 1) mx = fmaxf(mx, __shfl_xor(mx, o));
  float sum = 0.f;
  float ev[4];
#pragma unroll
  for (int p = 0; p < 4; ++p) {
    ev[p] = __expf(sv[p] - mx);
    sum += ev[p];
  }
#pragma unroll
  for (int o = 32; o; o >>= 1) sum += __shfl_xor(sum, o);
  float rs = 1.f / sum;
#pragma unroll
  for (int p = 0; p < 4; ++p) {
    if (p >= np) continue;
    int k = p * 64 + lane;
    if (k < Lc) sArow[wave][k] = ev[p] * rs;
  }
  for (int k = q + 1 + lane; k < 204; k += 64) sArow[wave][k] = 0.f;
  int half = lane >> 5, li = lane & 31;
  const uint* Vu = (const uint*)V16 + rl(b * Lc * (Hc / 2) + h * (HSc / 2)) + li;
  float acc0 = 0.f, acc1 = 0.f, acc2 = 0.f, acc3 = 0.f;
  for (int k0 = 0; k0 <= q; k0 += 4) {
    int ka = k0 + half;
    int kb = k0 + 2 + half;
    int kca = (ka <= q) ? ka : q;
    int kcb = (kb <= q) ? kb : q;
    float aa = sArow[wave][ka];
    float ab = sArow[wave][kb];
    int ti0 = tmr[kca], di0 = dmr[kca];
    int ti1 = tmr[kcb], di1 = dmr[kcb];
    uint tv0 = tVs[ti0 * TROW + li];
    uint dv0 = dVs[di0 * TROW + li];
    uint vv0 = Vu[kca * (Hc / 2)];
    uint tv1 = tVs[ti1 * TROW + li];
    uint dv1 = dVs[di1 * TROW + li];
    uint vv1 = Vu[kcb * (Hc / 2)];
    h2 s0 = u2h(tv0) + u2h(dv0) + u2h(vv0);
    h2 s1 = u2h(tv1) + u2h(dv1) + u2h(vv1);
    acc0 = fmaf(aa, (float)s0.x, acc0);
    acc1 = fmaf(aa, (float)s0.y, acc1);
    acc2 = fmaf(ab, (float)s1.x, acc2);
    acc3 = fmaf(ab, (float)s1.y, acc3);
  }
  float accLo = acc0 + acc2; accLo += __shfl_xor(accLo, 32);
  float accHi = acc1 + acc3; accHi += __shfl_xor(accHi, 32);
  if (half == 0) {
    int oib = m * Hc + h * HSc + 2 * li;
    float2 qv = *(const float2*)&Qn[oib];
    float2 r;
    r.x = qv.x + accLo;
    r.y = qv.y + accHi;
    *(float2*)&seqs[oib] = r;
  }
}

// ---------------- fused LN2 + FFN1(relu) + FFN2 + residual + keep [+ lnf] ---
template <int FIN>
__global__ __launch_bounds__(512)
void ffn_k(float* __restrict__ seqs,
           const float* __restrict__ g, const float* __restrict__ bt,
           const ushort* __restrict__ W1_16, const float* __restrict__ b1,
           const ushort* __restrict__ W2_16, const float* __restrict__ b2,
           const int* __restrict__ logs,
           const float* __restrict__ lnf_g, const float* __restrict__ lnf_b,
           float* __restrict__ dout) {
  __shared__ __fp16 Xl[16][LDH];
  __shared__ __fp16 Hl[16][LDH];
  __shared__ __fp16 Wl[128][LDH];
  __shared__ float Ol[16][Hc];
  int m0 = blockIdx.x * 16;
  int t = threadIdx.x;
  {
    int r = t >> 5, c0 = (t & 31) * 8;
    const float* xr = &seqs[(m0 + r) * Hc + c0];
    float4 v0 = *(const float4*)&xr[0];
    float4 v1 = *(const float4*)&xr[4];
    float s = v0.x + v0.y + v0.z + v0.w + v1.x + v1.y + v1.z + v1.w;
    float q = v0.x*v0.x + v0.y*v0.y + v0.z*v0.z + v0.w*v0.w
            + v1.x*v1.x + v1.y*v1.y + v1.z*v1.z + v1.w*v1.w;
#pragma unroll
    for (int o = 1; o < 32; o <<= 1) { s += __shfl_xor(s, o); q += __shfl_xor(q, o); }
    float mean = s * (1.f / Hc);
    float var = q * (1.f / Hc) - mean * mean;
    float rstd = 1.f / sqrtf(var + 1e-8f);
    float tmp[8] = {v0.x,v0.y,v0.z,v0.w,v1.x,v1.y,v1.z,v1.w};
    float nv[8];
#pragma unroll
    for (int j = 0; j < 8; ++j)
      nv[j] = (tmp[j] - mean) * rstd * g[c0 + j] + bt[c0 + j];
#pragma unroll
    for (int j = 0; j < 8; j += 2)
      *(h2*)&Xl[r][c0 + j] = __builtin_amdgcn_cvt_pkrtz(nv[j], nv[j + 1]);
  }
  int wave = t >> 6, lane = t & 63;
  int row = lane & 15, kg = lane >> 4;
#pragma unroll
  for (int ch = 0; ch < 2; ++ch) {
    __syncthreads();
    for (int i = t; i < 4096; i += 512) {
      int r = i >> 5, c = (i & 31) * 8;
      uint4 v = *(const uint4*)&W1_16[(ch * 128 + r) * Hc + c];
      *(uint4*)&Wl[r][c] = v;
    }
    __syncthreads();
    int bn = wave * 16 + row;
    f32x4 acc = {0.f, 0.f, 0.f, 0.f};
#pragma unroll
    for (int k0 = 0; k0 < Hc; k0 += 32) {
      int kk = k0 + kg * 8;
      f16x8 a = *(const f16x8*)&Xl[row][kk];
      f16x8 bb = *(const f16x8*)&Wl[bn][kk];
      acc = __builtin_amdgcn_mfma_f32_16x16x32_f16(a, bb, acc, 0, 0, 0);
    }
    int coln = ch * 128 + wave * 16 + row;
    float bv = b1[coln];
#pragma unroll
    for (int r = 0; r < 4; ++r) {
      float v = fmaxf(acc[r] + bv, 0.f);
      Hl[kg * 4 + r][coln] = (_Float16)v;
    }
  }
#pragma unroll
  for (int ch = 0; ch < 2; ++ch) {
    __syncthreads();
    for (int i = t; i < 4096; i += 512) {
      int r = i >> 5, c = (i & 31) * 8;
      uint4 v = *(const uint4*)&W2_16[(ch * 128 + r) * Hc + c];
      *(uint4*)&Wl[r][c] = v;
    }
    __syncthreads();
    int bn = wave * 16 + row;
    f32x4 acc = {0.f, 0.f, 0.f, 0.f};
#pragma unroll
    for (int k0 = 0; k0 < Hc; k0 += 32) {
      int kk = k0 + kg * 8;
      f16x8 a = *(const f16x8*)&Hl[row][kk];
      f16x8 bb = *(const f16x8*)&Wl[bn][kk];
      acc = __builtin_amdgcn_mfma_f32_16x16x32_f16(a, bb, acc, 0, 0, 0);
    }
    int coln = ch * 128 + wave * 16 + row;
    float bv = b2[coln];
#pragma unroll
    for (int r = 0; r < 4; ++r) {
      int mrow = kg * 4 + r;
      int m = m0 + mrow;
      float keep = (logs[m] != 0) ? 1.f : 0.f;
      float xv = h2f(__builtin_bit_cast(ushort, Xl[mrow][coln]));
      float val = (acc[r] + bv + xv) * keep;
      if (FIN) Ol[mrow][coln] = val;
      else     seqs[m * Hc + coln] = val;
    }
  }
  if (FIN) {
    __syncthreads();
    int r = t >> 5, c0 = (t & 31) * 8;
    float v[8];
#pragma unroll
    for (int j = 0; j < 8; ++j) v[j] = Ol[r][c0 + j];
    float s = 0.f, q = 0.f;
#pragma unroll
    for (int j = 0; j < 8; ++j) { s += v[j]; q += v[j] * v[j]; }
#pragma unroll
    for (int o = 1; o < 32; o <<= 1) { s += __shfl_xor(s, o); q += __shfl_xor(q, o); }
    float mean = s * (1.f / Hc);
    float var = q * (1.f / Hc) - mean * mean;
    float rstd = 1.f / sqrtf(var + 1e-8f);
#pragma unroll
    for (int j = 0; j < 8; ++j)
      dout[(m0 + r) * Hc + c0 + j] = (v[j] - mean) * rstd * lnf_g[c0 + j] + lnf_b[c0 + j];
  }
}

extern "C" void kernel_launch(void* const* d_in, const int* in_sizes, int n_in,
                              void* d_out, int out_size, void* d_ws, size_t ws_size,
                              hipStream_t stream) {
  const int* logs = (const int*)d_in[0];
  const int* tm   = (const int*)d_in[1];
  const int* dm   = (const int*)d_in[2];
  const float* item = (const float*)d_in[3];
  const float* pK = (const float*)d_in[4];
  const float* pV = (const float*)d_in[5];
  const float* tK = (const float*)d_in[6];
  const float* tV = (const float*)d_in[7];
  const float* dK = (const float*)d_in[8];
  const float* dV = (const float*)d_in[9];
  const float* ln1_g = (const float*)d_in[10];
  const float* ln1_b = (const float*)d_in[11];
  const float* Wq = (const float*)d_in[12];
  const float* bq = (const float*)d_in[13];
  const float* Wk = (const float*)d_in[14];
  const float* bk = (const float*)d_in[15];
  const float* Wv = (const float*)d_in[16];
  const float* bv = (const float*)d_in[17];
  const float* ln2_g = (const float*)d_in[18];
  const float* ln2_b = (const float*)d_in[19];
  const float* W1 = (const float*)d_in[20];
  const float* b1 = (const float*)d_in[21];
  const float* W2 = (const float*)d_in[22];
  const float* b2 = (const float*)d_in[23];
  const float* lnf_g = (const float*)d_in[24];
  const float* lnf_b = (const float*)d_in[25];

  const int NROW = Mtot * Hc;          // 204800 floats
  float* ws = (float*)d_ws;
  float* sSeqs = ws + 0 * NROW;
  float* sQn   = ws + 1 * NROW;
  ushort* Q16  = (ushort*)(ws + 2 * NROW);
  ushort* K16  = Q16 + NROW;
  ushort* V16  = K16 + NROW;
  ushort* w16  = (ushort*)(ws + 4 * NROW);   // 5*WN + 4*TN halves
  ushort* wq16 = w16 + 0 * WN;
  ushort* wk16 = w16 + 1 * WN;
  ushort* wv16 = w16 + 2 * WN;
  ushort* w116 = w16 + 3 * WN;
  ushort* w216 = w16 + 4 * WN;
  ushort* tK16 = w16 + 5 * WN;
  ushort* tV16 = tK16 + TN;
  ushort* dK16 = tV16 + TN;
  ushort* dV16 = dK16 + TN;

  dim3 gC(64, 9);
  cvtw_k<<<gC, 256, 0, stream>>>(Wq, Wk, Wv, W1, W2, tK, tV, dK, dV, w16);

  dim3 gQKV(Mtot / 16, 12);
  dim3 ga(NHc, Bc, 16);
  const int HHh = Hc * Hc;
  for (int i = 0; i < NBc; ++i) {
    mmqkv_k<<<gQKV, 256, 0, stream>>>(sSeqs, item, logs, (i == 0) ? 1 : 0,
                                      ln1_g + i * Hc, ln1_b + i * Hc,
                                      wq16 + i * HHh, wk16 + i * HHh, wv16 + i * HHh,
                                      bq + i * Hc, bk + i * Hc, bv + i * Hc,
                                      pK, pV, sQn, Q16, K16, V16);
    attn_k<<<ga, 1024, 0, stream>>>(Q16, K16, V16,
                                    tK16, dK16, tV16, dV16,
                                    tm, dm, logs, sQn, sSeqs);
    if (i == 0)
      ffn_k<0><<<Mtot / 16, 512, 0, stream>>>(sSeqs, ln2_g + i * Hc, ln2_b + i * Hc,
                                              w116 + i * HHh, b1 + i * Hc,
                                              w216 + i * HHh, b2 + i * Hc, logs,
                                              nullptr, nullptr, nullptr);
    else
      ffn_k<1><<<Mtot / 16, 512, 0, stream>>>(sSeqs, ln2_g + i * Hc, ln2_b + i * Hc,
                                              w116 + i * HHh, b1 + i * Hc,
                                              w216 + i * HHh, b2 + i * Hc, logs,
                                              lnf_g, lnf_b, (float*)d_out);
  }
}